// Round 17
// baseline (180.463 us; speedup 1.0000x reference)
//
#include <hip/hip_runtime.h>
#include <hip/hip_bf16.h>
#include <math.h>

#define B_ 2
#define N_ 1024
#define H_ 512
#define NH_ 8
#define HD_ 64
#define G_ 50
#define TAB_ 1024
constexpr float MAXD = 10.0f;

typedef __attribute__((ext_vector_type(8))) short short8;
typedef __attribute__((ext_vector_type(4))) float f32x4;

__device__ inline ushort f2bf(float v) {
  __hip_bfloat16 h = __float2bfloat16(v);
  return *(ushort*)&h;
}
__device__ inline float bf2f(ushort u) {
  unsigned x = ((unsigned)u) << 16;
  return __uint_as_float(x);
}
__device__ inline void gload_lds16(const ushort* g, ushort* l) {
  __builtin_amdgcn_global_load_lds(
      (const __attribute__((address_space(1))) void*)g,
      (__attribute__((address_space(3))) void*)l, 16, 0, 0);
}

// ---------------- fused prep: 3 weight transposes + bias table + LN1 ----------------
__device__ inline void transp_dev(const float* __restrict__ src,
                                  ushort* __restrict__ d, int R, int C,
                                  int bx, int by, int t, float (*tile)[33]) {
  int r0 = by * 32, c0 = bx * 32;
  int rr = t >> 5, cc = t & 31;
  #pragma unroll
  for (int p = 0; p < 4; ++p)
    tile[rr + p * 8][cc] = src[(size_t)(r0 + rr + p * 8) * C + c0 + cc];
  __syncthreads();
  #pragma unroll
  for (int p = 0; p < 4; ++p)
    d[(size_t)(c0 + rr + p * 8) * R + r0 + cc] = f2bf(tile[cc][rr + p * 8]);
}

__global__ __launch_bounds__(256) void prep_k(
    const float* wq, const float* wk, const float* wv, const float* wo,
    const float* w1, const float* w2, ushort* __restrict__ wT4,
    ushort* __restrict__ w1T, ushort* __restrict__ w2T,
    const float* __restrict__ widths, const float* __restrict__ dp_w,
    const float* __restrict__ dp_b, float2* __restrict__ tab2,
    const float* __restrict__ x, const float* __restrict__ ln1g,
    const float* __restrict__ ln1b, ushort* __restrict__ xn) {
  __shared__ float tile[32][33];
  __shared__ float red2[4][2];
  int bid = blockIdx.x, t = threadIdx.x;
  if (bid < 1024) {
    int z = bid >> 8, rem = bid & 255;
    const float* src = (z == 0) ? wq : (z == 1) ? wk : (z == 2) ? wv : wo;
    transp_dev(src, wT4 + (size_t)z * 512 * 512, 512, 512, rem & 15, rem >> 4, t, tile);
  } else if (bid < 2048) {
    int rem = bid - 1024;
    transp_dev(w1, w1T, 512, 2048, rem & 63, rem >> 6, t, tile);
  } else if (bid < 3072) {
    int rem = bid - 2048;
    transp_dev(w2, w2T, 2048, 512, rem & 15, rem >> 4, t, tile);
  } else if (bid < 3105) {
    int i = (bid - 3072) * 256 + t;
    if (i >= NH_ * (TAB_ + 1)) return;
    int h = i / (TAB_ + 1), tt = i % (TAB_ + 1);
    int t1 = tt < TAB_ ? tt + 1 : tt;
    float d0 = (float)tt * (MAXD / TAB_);
    float d1 = (float)t1 * (MAXD / TAB_);
    float v0 = dp_b[h], v1 = dp_b[h];
    for (int g = 0; g < G_; ++g) {
      float c = (float)g * (MAXD / 49.0f);
      float w = widths[g];
      float inv = -1.0f / (2.0f * w * w);
      float wg = dp_w[g * NH_ + h];
      float e0 = d0 - c, e1 = d1 - c;
      v0 += expf(e0 * e0 * inv) * wg;
      v1 += expf(e1 * e1 * inv) * wg;
    }
    tab2[i] = make_float2(v0, v1);
  } else {
    // LN1: 2 rows per block (128 threads each)
    int row = (bid - 3105) * 2 + (t >> 7);
    int tl = t & 127;
    float4 v = *(const float4*)(x + (size_t)row * H_ + tl * 4);
    float s = v.x + v.y + v.z + v.w;
    float sq = v.x * v.x + v.y * v.y + v.z * v.z + v.w * v.w;
    #pragma unroll
    for (int m = 1; m < 64; m <<= 1) {
      s += __shfl_xor(s, m, 64);
      sq += __shfl_xor(sq, m, 64);
    }
    int wid = t >> 6;
    if ((t & 63) == 0) { red2[wid][0] = s; red2[wid][1] = sq; }
    __syncthreads();
    int rw = (t >> 7) * 2;
    s = red2[rw][0] + red2[rw + 1][0];
    sq = red2[rw][1] + red2[rw + 1][1];
    float mu = s * (1.0f / H_);
    float var = sq * (1.0f / H_) - mu * mu;
    float rs = rsqrtf(var + 1e-5f);
    float4 gg = *(const float4*)(ln1g + tl * 4);
    float4 bb = *(const float4*)(ln1b + tl * 4);
    ushort4 o;
    o.x = f2bf((v.x - mu) * rs * gg.x + bb.x);
    o.y = f2bf((v.y - mu) * rs * gg.y + bb.y);
    o.z = f2bf((v.z - mu) * rs * gg.z + bb.z);
    o.w = f2bf((v.w - mu) * rs * gg.w + bb.w);
    *(ushort4*)(xn + (size_t)row * H_ + tl * 4) = o;
  }
}

// ---------------- bf16 MFMA GEMM, global_load_lds 2-phase double-buffer ----------
enum { EPI_QKV = 1, EPI_RES = 2, EPI_GELU = 3, EPI_PART = 4 };

template <int BM, int BN, int EPI>
__global__ __launch_bounds__(256) void mfma_gemm(const ushort* __restrict__ A,
                                                 const ushort* __restrict__ Bt,
                                                 const float* __restrict__ b0,
                                                 const float* __restrict__ b1,
                                                 const float* __restrict__ b2,
                                                 const float* __restrict__ resid,
                                                 void* __restrict__ outv,
                                                 int K, int Ks, int Nc) {
  __shared__ ushort As[2][BM * 32];
  __shared__ ushort Bs[2][BN * 32];
  int t = threadIdx.x;
  int z = blockIdx.z;
  const ushort* Bz = Bt + (size_t)z * Nc * Ks;
  const float* bias = (z == 0) ? b0 : (z == 1) ? b1 : b2;
  int m0 = blockIdx.y * BM, n0 = blockIdx.x * BN;
  int lane = t & 63, w = t >> 6, wr = w >> 1, wc = w & 1;
  int lrow = lane & 15, lkg = lane >> 4;
  constexpr int NFM = BM / 32, NFN = BN / 32;
  constexpr int AL = BM / 64, BL = BN / 64;
  f32x4 acc[NFM][NFN] = {};
  int rl = lane >> 2, kgl = lane & 3;

  auto stage = [&](int buf, int kt) {
    #pragma unroll
    for (int p = 0; p < AL; ++p) {
      int r = w * (BM / 4) + p * 16 + rl;
      int kgs = kgl ^ (r & 3);
      gload_lds16(&A[(size_t)(m0 + r) * Ks + kt + kgs * 8],
                  &As[buf][(w * (BM / 4) + p * 16) * 32]);
    }
    #pragma unroll
    for (int p = 0; p < BL; ++p) {
      int r = w * (BN / 4) + p * 16 + rl;
      int kgs = kgl ^ (r & 3);
      gload_lds16(&Bz[(size_t)(n0 + r) * Ks + kt + kgs * 8],
                  &Bs[buf][(w * (BN / 4) + p * 16) * 32]);
    }
  };
  auto compute = [&](int buf) {
    short8 af[NFM], bfr[NFN];
    #pragma unroll
    for (int fm = 0; fm < NFM; ++fm) {
      int r = wr * (BM / 2) + fm * 16 + lrow;
      af[fm] = *(const short8*)&As[buf][r * 32 + ((lkg ^ (r & 3)) << 3)];
    }
    #pragma unroll
    for (int fn = 0; fn < NFN; ++fn) {
      int r = wc * (BN / 2) + fn * 16 + lrow;
      bfr[fn] = *(const short8*)&Bs[buf][r * 32 + ((lkg ^ (r & 3)) << 3)];
    }
    #pragma unroll
    for (int fm = 0; fm < NFM; ++fm)
      #pragma unroll
      for (int fn = 0; fn < NFN; ++fn)
        acc[fm][fn] = __builtin_amdgcn_mfma_f32_16x16x32_bf16(af[fm], bfr[fn],
                                                              acc[fm][fn], 0, 0, 0);
  };

  stage(0, 0);
  __syncthreads();
  int cur = 0;
  for (int kt = 0; kt < K; kt += 32) {
    if (kt + 32 < K) stage(cur ^ 1, kt + 32);
    compute(cur);
    __syncthreads();
    cur ^= 1;
  }

  int rbase = (lane >> 4) * 4;
  if constexpr (EPI == EPI_QKV) {
    if (z < 2) {
      #pragma unroll
      for (int fm = 0; fm < NFM; ++fm)
        #pragma unroll
        for (int fn = 0; fn < NFN; ++fn)
          #pragma unroll
          for (int j = 0; j < 4; ++j) {
            int row = m0 + wr * (BM / 2) + fm * 16 + rbase + j;
            int col = n0 + wc * (BN / 2) + fn * 16 + lrow;
            float v = acc[fm][fn][j] + bias[col];
            ushort* q = (ushort*)outv + (size_t)z * (1 << 20);
            int bb = row >> 10, n = row & (N_ - 1);
            int h = col >> 6, d = col & 63;
            q[(((size_t)(bb * NH_ + h)) * N_ + n) * HD_ + d] = f2bf(v);
          }
    } else {
      // V: transpose via LDS, write coalesced 32B/thread lines along n
      __shared__ float vtile[64 * 65];
      #pragma unroll
      for (int fm = 0; fm < NFM; ++fm)
        #pragma unroll
        for (int fn = 0; fn < NFN; ++fn)
          #pragma unroll
          for (int j = 0; j < 4; ++j) {
            int rloc = wr * (BM / 2) + fm * 16 + rbase + j;
            int cloc = wc * (BN / 2) + fn * 16 + lrow;
            vtile[rloc * 65 + cloc] = acc[fm][fn][j] + bias[n0 + cloc];
          }
      __syncthreads();
      int d_ = t & 63, nc = t >> 6;
      int h = n0 >> 6;
      int bb = m0 >> 10, nbase = m0 & (N_ - 1);
      ushort* dst = (ushort*)outv + (size_t)2 * (1 << 20) +
                    (((size_t)(bb * NH_ + h)) * HD_ + d_) * N_ + nbase + nc * 16;
      short8 o0, o1;
      #pragma unroll
      for (int i = 0; i < 8; ++i) {
        o0[i] = (short)f2bf(vtile[(nc * 16 + i) * 65 + d_]);
        o1[i] = (short)f2bf(vtile[(nc * 16 + 8 + i) * 65 + d_]);
      }
      *(short8*)&dst[0] = o0;
      *(short8*)&dst[8] = o1;
    }
  } else {
    #pragma unroll
    for (int fm = 0; fm < NFM; ++fm) {
      #pragma unroll
      for (int fn = 0; fn < NFN; ++fn) {
        #pragma unroll
        for (int j = 0; j < 4; ++j) {
          int row = m0 + wr * (BM / 2) + fm * 16 + rbase + j;
          int col = n0 + wc * (BN / 2) + fn * 16 + lrow;
          float v = acc[fm][fn][j] + bias[col];
          if constexpr (EPI == EPI_RES) {
            ((float*)outv)[(size_t)row * Nc + col] =
                resid[(size_t)row * Nc + col] + v;
          } else {  // GELU -> bf16
            ((ushort*)outv)[(size_t)row * Nc + col] =
                f2bf(0.5f * v * (1.0f + erff(v * 0.70710678118654752f)));
          }
        }
      }
    }
  }
}

// ---------------- 512-thread GEMM, in-block K-split x2 + LDS reduce ----------
template <int EPI>
__global__ __launch_bounds__(512) void mfma_gemm2(const ushort* __restrict__ A,
                                                  const ushort* __restrict__ Bt,
                                                  const float* __restrict__ bias,
                                                  const float* __restrict__ resid,
                                                  void* __restrict__ outv,
                                                  int K, int Ks, int Nc) {
  constexpr int BM = 64, BN = 64;
  __shared__ ushort AsBs[2][2][2][BM * 32];  // [A/B][half][buf]
  int t = threadIdx.x;
  int half = t >> 8;
  int lane = t & 63;
  int wl = (t >> 6) & 3;  // wave within half
  int wr = wl >> 1, wc = wl & 1;
  int lrow = lane & 15, lkg = lane >> 4;
  int k0 = half * K;
  int m0 = blockIdx.y * BM, n0 = blockIdx.x * BN;
  f32x4 acc[2][2] = {};
  int rl = lane >> 2, kgl = lane & 3;

  auto stage = [&](int buf, int kt) {
    int r = wl * 16 + rl;
    int kgs = kgl ^ (r & 3);
    gload_lds16(&A[(size_t)(m0 + r) * Ks + k0 + kt + kgs * 8],
                &AsBs[0][half][buf][(wl * 16) * 32]);
    gload_lds16(&Bt[(size_t)(n0 + r) * Ks + k0 + kt + kgs * 8],
                &AsBs[1][half][buf][(wl * 16) * 32]);
  };
  auto compute = [&](int buf) {
    short8 af[2], bfr[2];
    #pragma unroll
    for (int fm = 0; fm < 2; ++fm) {
      int r = wr * 32 + fm * 16 + lrow;
      af[fm] = *(const short8*)&AsBs[0][half][buf][r * 32 + ((lkg ^ (r & 3)) << 3)];
    }
    #pragma unroll
    for (int fn = 0; fn < 2; ++fn) {
      int r = wc * 32 + fn * 16 + lrow;
      bfr[fn] = *(const short8*)&AsBs[1][half][buf][r * 32 + ((lkg ^ (r & 3)) << 3)];
    }
    #pragma unroll
    for (int fm = 0; fm < 2; ++fm)
      #pragma unroll
      for (int fn = 0; fn < 2; ++fn)
        acc[fm][fn] = __builtin_amdgcn_mfma_f32_16x16x32_bf16(af[fm], bfr[fn],
                                                              acc[fm][fn], 0, 0, 0);
  };

  stage(0, 0);
  __syncthreads();
  int cur = 0;
  for (int kt = 0; kt < K; kt += 32) {
    if (kt + 32 < K) stage(cur ^ 1, kt + 32);
    compute(cur);
    __syncthreads();
    cur ^= 1;
  }

  // cross-half reduce via LDS (aliases AsBs; all LDS reads drained by last barrier)
  float* red = (float*)&AsBs[0][0][0][0];  // 64*65 f32 = 16.6 KB of 32 KB
  int rbase = (lane >> 4) * 4;
  if (half == 1) {
    #pragma unroll
    for (int fm = 0; fm < 2; ++fm)
      #pragma unroll
      for (int fn = 0; fn < 2; ++fn)
        #pragma unroll
        for (int j = 0; j < 4; ++j) {
          int rloc = wr * 32 + fm * 16 + rbase + j;
          int cloc = wc * 32 + fn * 16 + lrow;
          red[rloc * 65 + cloc] = acc[fm][fn][j];
        }
  }
  __syncthreads();
  if (half == 0) {
    #pragma unroll
    for (int fm = 0; fm < 2; ++fm)
      #pragma unroll
      for (int fn = 0; fn < 2; ++fn)
        #pragma unroll
        for (int j = 0; j < 4; ++j) {
          int rloc = wr * 32 + fm * 16 + rbase + j;
          int cloc = wc * 32 + fn * 16 + lrow;
          float sum = acc[fm][fn][j] + red[rloc * 65 + cloc];
          int row = m0 + rloc, col = n0 + cloc;
          if constexpr (EPI == EPI_PART) {
            ((float*)outv)[(size_t)row * Nc + col] = sum;
          } else {  // EPI_RES
            ((float*)outv)[(size_t)row * Nc + col] =
                resid[(size_t)row * Nc + col] + sum + bias[col];
          }
        }
  }
}

// ---------------- fused K-split combine + LayerNorm (x1 f32 + xn bf16) ----------
__global__ __launch_bounds__(128) void comb2ln_k(const float* __restrict__ p,
                                                 const float* __restrict__ resid,
                                                 const float* __restrict__ bias,
                                                 const float* __restrict__ g,
                                                 const float* __restrict__ bl,
                                                 float* __restrict__ x1out,
                                                 ushort* __restrict__ xnout) {
  int row = blockIdx.x, t = threadIdx.x;
  int base = row * H_ + t * 4;
  f32x4 a = *(const f32x4*)&p[base];
  f32x4 r = *(const f32x4*)&resid[base];
  f32x4 bi = *(const f32x4*)&bias[t * 4];
  f32x4 v = r + a + bi;
  *(f32x4*)&x1out[base] = v;
  float s = v[0] + v[1] + v[2] + v[3];
  float sq = v[0] * v[0] + v[1] * v[1] + v[2] * v[2] + v[3] * v[3];
  #pragma unroll
  for (int m = 1; m < 64; m <<= 1) {
    s += __shfl_xor(s, m, 64);
    sq += __shfl_xor(sq, m, 64);
  }
  __shared__ float red[2][2];
  int wid = t >> 6;
  if ((t & 63) == 0) { red[wid][0] = s; red[wid][1] = sq; }
  __syncthreads();
  s = red[0][0] + red[1][0];
  sq = red[0][1] + red[1][1];
  float mu = s * (1.0f / H_);
  float var = sq * (1.0f / H_) - mu * mu;
  float rs = rsqrtf(var + 1e-5f);
  float4 gg = *(const float4*)(g + t * 4);
  float4 bb = *(const float4*)(bl + t * 4);
  ushort4 o;
  o.x = f2bf((v[0] - mu) * rs * gg.x + bb.x);
  o.y = f2bf((v[1] - mu) * rs * gg.y + bb.y);
  o.z = f2bf((v[2] - mu) * rs * gg.z + bb.z);
  o.w = f2bf((v[3] - mu) * rs * gg.w + bb.w);
  *(ushort4*)(xnout + (size_t)row * H_ + t * 4) = o;
}

// ---------------- MFMA flash attention, j-split, dbuf LDS, fused tail-combine ----
constexpr int QT = 64, KT = 64, NJH = 2, NTH = N_ / (KT * NJH);  // 8 tiles/block
constexpr int JH = N_ / NJH;  // 512

__global__ __launch_bounds__(256) void attn_k(
    const ushort* __restrict__ q, const ushort* __restrict__ k,
    const ushort* __restrict__ v, const float* __restrict__ dist,
    const int* __restrict__ mask, const float2* __restrict__ tab2g,
    float* __restrict__ Op, float2* __restrict__ ml,
    unsigned* __restrict__ flags, ushort* __restrict__ aout) {
  int qt = blockIdx.x, h = blockIdx.y, z = blockIdx.z;
  int b = z >> 1, jh = z & 1;
  int i0 = qt * QT;
  int jbase = jh * JH;
  __shared__ ushort Ks[2][KT * 64];  // [j][d], chunk ^= (j&7)
  __shared__ ushort Vt[2][64 * KT];  // [d][j], chunk ^= (d&7)
  __shared__ ushort Ps[4][16 * 64];  // per-warp P [q][j], chunk ^= (q&7)
  __shared__ float2 tl2[TAB_ + 1];
  __shared__ float mfl[JH];
  __shared__ int lastflag;
  int t = threadIdx.x;
  int lane = t & 63, w = t >> 6;
  int l = lane & 15, g = lane >> 4;

  for (int i = t; i <= TAB_; i += 256) tl2[i] = tab2g[h * (TAB_ + 1) + i];
  for (int i = t; i < JH; i += 256) mfl[i] = (mask[b * N_ + jbase + i] == 0) ? -1e9f : 0.0f;

  const size_t ho = ((size_t)(b * NH_ + h)) * N_ * HD_;
  const ushort* qb = q + ho;
  const ushort* kb = k + ho;
  const ushort* vb = v + ho;  // V^T layout: [d][N_]

  int qloc = w * 16 + 4 * g;
  int qrow = i0 + w * 16 + l;
  short8 qf[2];
  qf[0] = *(const short8*)&qb[(size_t)qrow * 64 + g * 8];
  qf[1] = *(const short8*)&qb[(size_t)qrow * 64 + 32 + g * 8];

  int c2 = t & 7, jr = t >> 3;  // K/V staging: chunk 0..7, row 0..31 (+32)

  auto stK = [&](int buf, short8 val, int j2) {
    *(short8*)&Ks[buf][j2 * 64 + ((c2 ^ (j2 & 7)) << 3)] = val;
  };
  auto stV = [&](int buf, short8 val, int d) {
    *(short8*)&Vt[buf][d * 64 + ((c2 ^ (d & 7)) << 3)] = val;
  };

  // dist in MFMA S-layout: row = i0+qloc+reg, col = jbase + tt*KT + fj*16 + l
  const float* dbase = dist + ((size_t)b * N_ + (i0 + qloc)) * N_ + jbase + l;

  // --- prologue: load + stage tile 0 ---
  short8 k0a, k1a, v0a, v1a;
  float ddc[4][4], ddn[4][4];
  {
    const ushort* kn = kb + (size_t)jbase * 64;
    const ushort* vn = vb + jbase;
    k0a = *(const short8*)&kn[(size_t)jr * 64 + c2 * 8];
    k1a = *(const short8*)&kn[(size_t)(jr + 32) * 64 + c2 * 8];
    v0a = *(const short8*)&vn[(size_t)jr * N_ + c2 * 8];
    v1a = *(const short8*)&vn[(size_t)(jr + 32) * N_ + c2 * 8];
    #pragma unroll
    for (int reg = 0; reg < 4; ++reg)
      #pragma unroll
      for (int fj = 0; fj < 4; ++fj)
        ddc[reg][fj] = dbase[(size_t)reg * N_ + fj * 16];
  }
  __syncthreads();  // tl2 + mfl ready
  stK(0, k0a, jr); stK(0, k1a, jr + 32);
  stV(0, v0a, jr); stV(0, v1a, jr + 32);
  __syncthreads();

  float m_[4] = {-1e30f, -1e30f, -1e30f, -1e30f};
  float l_[4] = {0.f, 0.f, 0.f, 0.f};
  f32x4 acc[4] = {{0,0,0,0},{0,0,0,0},{0,0,0,0},{0,0,0,0}};

  int cur = 0;
  for (int tt = 0; tt < NTH; ++tt) {
    const int j0 = jbase + tt * KT;
    if (tt + 1 < NTH) {
      const ushort* kn = kb + (size_t)(j0 + KT) * 64;
      const ushort* vn = vb + (j0 + KT);
      k0a = *(const short8*)&kn[(size_t)jr * 64 + c2 * 8];
      k1a = *(const short8*)&kn[(size_t)(jr + 32) * 64 + c2 * 8];
      v0a = *(const short8*)&vn[(size_t)jr * N_ + c2 * 8];
      v1a = *(const short8*)&vn[(size_t)(jr + 32) * N_ + c2 * 8];
      #pragma unroll
      for (int reg = 0; reg < 4; ++reg)
        #pragma unroll
        for (int fj = 0; fj < 4; ++fj)
          ddn[reg][fj] = dbase[(size_t)reg * N_ + (tt + 1) * KT + fj * 16];
    }
    // S = Q K^T
    f32x4 sa[4] = {{0,0,0,0},{0,0,0,0},{0,0,0,0},{0,0,0,0}};
    __builtin_amdgcn_s_setprio(1);
    #pragma unroll
    for (int dblk = 0; dblk < 2; ++dblk)
      #pragma unroll
      for (int fj = 0; fj < 4; ++fj) {
        int j2 = fj * 16 + l;
        short8 kf = *(const short8*)&Ks[cur][j2 * 64 + (((dblk * 4 + g) ^ (j2 & 7)) << 3)];
        sa[fj] = __builtin_amdgcn_mfma_f32_16x16x32_bf16(qf[dblk], kf, sa[fj], 0, 0, 0);
      }
    __builtin_amdgcn_s_setprio(0);
    // softmax: bias = table-lerp(dist in regs) + mask
    float al_[4];
    #pragma unroll
    for (int reg = 0; reg < 4; ++reg) {
      float svr[4];
      #pragma unroll
      for (int fj = 0; fj < 4; ++fj) {
        float u = ddc[reg][fj] * ((float)TAB_ / MAXD);
        int it = (int)u;
        it = it < 0 ? 0 : (it > TAB_ - 1 ? TAB_ - 1 : it);
        float f = u - (float)it;
        float2 tv = tl2[it];
        float bias = tv.x + f * (tv.y - tv.x) + mfl[tt * KT + fj * 16 + l];
        svr[fj] = fmaf(sa[fj][reg], 0.125f, bias);
      }
      float rm = fmaxf(fmaxf(svr[0], svr[1]), fmaxf(svr[2], svr[3]));
      rm = fmaxf(rm, __shfl_xor(rm, 1, 64));
      rm = fmaxf(rm, __shfl_xor(rm, 2, 64));
      rm = fmaxf(rm, __shfl_xor(rm, 4, 64));
      rm = fmaxf(rm, __shfl_xor(rm, 8, 64));
      float mn = fmaxf(m_[reg], rm);
      float al = __expf(m_[reg] - mn);
      m_[reg] = mn;
      al_[reg] = al;
      float ps = 0.f;
      int qlq = 4 * g + reg;
      #pragma unroll
      for (int fj = 0; fj < 4; ++fj) {
        float p = __expf(svr[fj] - mn);
        ps += p;
        int c = fj * 2 + (l >> 3);
        Ps[w][qlq * 64 + ((c ^ (qlq & 7)) << 3) + (l & 7)] = f2bf(p);
      }
      ps += __shfl_xor(ps, 1, 64);
      ps += __shfl_xor(ps, 2, 64);
      ps += __shfl_xor(ps, 4, 64);
      ps += __shfl_xor(ps, 8, 64);
      l_[reg] = l_[reg] * al + ps;
    }
    #pragma unroll
    for (int fd = 0; fd < 4; ++fd)
      #pragma unroll
      for (int reg = 0; reg < 4; ++reg) acc[fd][reg] *= al_[reg];
    // O += P V   (P A-frags, V^T B-frags)
    __builtin_amdgcn_s_setprio(1);
    #pragma unroll
    for (int jj = 0; jj < 2; ++jj) {
      short8 pa = *(const short8*)&Ps[w][l * 64 + (((jj * 4 + g) ^ (l & 7)) << 3)];
      #pragma unroll
      for (int fd = 0; fd < 4; ++fd) {
        int d2 = fd * 16 + l;
        short8 vf = *(const short8*)&Vt[cur][d2 * 64 + (((jj * 4 + g) ^ (d2 & 7)) << 3)];
        acc[fd] = __builtin_amdgcn_mfma_f32_16x16x32_bf16(pa, vf, acc[fd], 0, 0, 0);
      }
    }
    __builtin_amdgcn_s_setprio(0);
    // stage tile tt+1 into the other buffer (no race: readers use buf cur)
    if (tt + 1 < NTH) {
      int nb = cur ^ 1;
      stK(nb, k0a, jr); stK(nb, k1a, jr + 32);
      stV(nb, v0a, jr); stV(nb, v1a, jr + 32);
      #pragma unroll
      for (int reg = 0; reg < 4; ++reg)
        #pragma unroll
        for (int fj = 0; fj < 4; ++fj) ddc[reg][fj] = ddn[reg][fj];
    }
    __syncthreads();
    cur ^= 1;
  }
  // --- epilogue: write own unnormalized partials + (m,l) ---
  const size_t pbase = (((size_t)(b * NJH + jh) * NH_ + h) * N_) + i0;
  #pragma unroll
  for (int reg = 0; reg < 4; ++reg) {
    int rowl = qloc + reg;
    float* op = Op + (pbase + rowl) * HD_ + l;
    #pragma unroll
    for (int fd = 0; fd < 4; ++fd) op[fd * 16] = acc[fd][reg];
    if (l == 0) ml[pbase + rowl] = make_float2(m_[reg], l_[reg]);
  }
  // --- tail-block combine: last of the 2 j-halves merges and writes ao ---
  __threadfence();
  __syncthreads();
  if (t == 0) {
    unsigned old = atomicAdd(&flags[((unsigned)(b * NH_ + h)) * (N_ / QT) + qt], 1u);
    lastflag = (old == 1) ? 1 : 0;
  }
  __syncthreads();
  if (!lastflag) return;
  __threadfence();
  ushort* otile = (ushort*)&Ks[0][0];  // reuse: [64][68] bf16
  const size_t pother = (((size_t)(b * NJH + (jh ^ 1)) * NH_ + h) * N_) + i0;
  #pragma unroll
  for (int reg = 0; reg < 4; ++reg) {
    int rowl = qloc + reg;
    float2 mo = ml[pother + rowl];
    float M = fmaxf(m_[reg], mo.x);
    float aw = __expf(m_[reg] - M), ax = __expf(mo.x - M);
    float inv = 1.0f / (l_[reg] * aw + mo.y * ax);
    #pragma unroll
    for (int fd = 0; fd < 4; ++fd) {
      float oo = Op[(pother + rowl) * HD_ + fd * 16 + l];
      otile[rowl * 68 + fd * 16 + l] =
          f2bf((acc[fd][reg] * aw + oo * ax) * inv);
    }
  }
  __syncthreads();
  {
    int r = t >> 2, seg = t & 3;
    ushort* dst = aout + ((size_t)(b * N_ + i0 + r)) * H_ + h * HD_ + seg * 16;
    *(short8*)&dst[0] = *(const short8*)&otile[r * 68 + seg * 16];
    *(short8*)&dst[8] = *(const short8*)&otile[r * 68 + seg * 16 + 8];
  }
}

extern "C" void kernel_launch(void* const* d_in, const int* in_sizes, int n_in,
                              void* d_out, int out_size, void* d_ws, size_t ws_size,
                              hipStream_t stream) {
  const float* x = (const float*)d_in[0];
  const float* distances = (const float*)d_in[1];
  const int* mask = (const int*)d_in[2];
  const float* widths = (const float*)d_in[3];
  const float* dp_w = (const float*)d_in[4];
  const float* dp_b = (const float*)d_in[5];
  const float* wq = (const float*)d_in[6];
  const float* bq = (const float*)d_in[7];
  const float* wk = (const float*)d_in[8];
  const float* bk = (const float*)d_in[9];
  const float* wv = (const float*)d_in[10];
  const float* bv = (const float*)d_in[11];
  const float* wo = (const float*)d_in[12];
  const float* bo = (const float*)d_in[13];
  const float* ln1_g = (const float*)d_in[14];
  const float* ln1_b = (const float*)d_in[15];
  const float* ln2_g = (const float*)d_in[16];
  const float* ln2_b = (const float*)d_in[17];
  const float* w1 = (const float*)d_in[18];
  const float* b1 = (const float*)d_in[19];
  const float* w2 = (const float*)d_in[20];
  const float* b2 = (const float*)d_in[21];
  float* out = (float*)d_out;
  float* wsf = (float*)d_ws;

  const size_t M1 = (size_t)1 << 20;
  ushort* qkvb = (ushort*)wsf;                       // 3M bf16 (V transposed)
  float* x1 = wsf + 2 * M1;                          // 1M f32
  ushort* hbuf = (ushort*)(wsf + 3 * M1);            // 4M bf16
  ushort* xn = (ushort*)(wsf + 5 * M1);              // 1M bf16
  ushort* xn2 = (ushort*)(wsf + 5 * M1 + M1 / 2);
  ushort* ao = (ushort*)(wsf + 6 * M1);              // 1M bf16
  ushort* wT4 = (ushort*)(wsf + 6 * M1 + M1 / 2);    // 4x 512x512 bf16
  ushort* w1T = (ushort*)(wsf + 7 * M1);             // [2048][512] bf16
  ushort* w2T = (ushort*)(wsf + 7 * M1 + M1 / 2);    // [512][2048] bf16
  float2* tab2 = (float2*)(wsf + 8 * M1);            // 8200 float2
  float* Op = wsf + 9 * M1;                          // 2M f32 attn partials
  float2* ml = (float2*)(wsf + 11 * M1);             // 32K float2
  float* pAO = wsf + 12 * M1;                        // 1M f32 O-proj partial
  unsigned* flags = (unsigned*)(wsf + 13 * M1);      // 256 counters

  hipMemsetAsync(flags, 0, 256 * sizeof(unsigned), stream);

  prep_k<<<4129, 256, 0, stream>>>(wq, wk, wv, wo, w1, w2, wT4, w1T, w2T,
                                   widths, dp_w, dp_b, tab2, x, ln1_g, ln1_b, xn);

  mfma_gemm<64, 64, EPI_QKV><<<dim3(8, 32, 3), 256, 0, stream>>>(
      xn, wT4, bq, bk, bv, nullptr, qkvb, 512, 512, 512);

  attn_k<<<dim3(N_ / QT, NH_, B_ * NJH), 256, 0, stream>>>(
      qkvb, qkvb + M1, qkvb + 2 * M1, distances, mask, tab2, Op, ml, flags, ao);

  // attn-O projection: in-block K-split x2, single partial; fused combine+LN2
  mfma_gemm2<EPI_PART><<<dim3(8, 32), 512, 0, stream>>>(
      ao, wT4 + (size_t)3 * 512 * 512, bo, nullptr, pAO, 256, 512, 512);
  comb2ln_k<<<B_ * N_, 128, 0, stream>>>(pAO, x, bo, ln2_g, ln2_b, x1, xn2);

  // FFN1: 128x64 tiles -> 512 blocks (2/CU)
  mfma_gemm<128, 64, EPI_GELU><<<dim3(32, 16, 1), 256, 0, stream>>>(
      xn2, w1T, b1, b1, b1, nullptr, hbuf, 512, 512, 2048);

  // FFN2: in-block K-split x2, fully fused epilogue (resid + bias -> out)
  mfma_gemm2<EPI_RES><<<dim3(8, 32), 512, 0, stream>>>(
      hbuf, w2T, b2, x1, out, 1024, 2048, 512);
}

// Round 18
// 98.728 us; speedup vs baseline: 1.8279x; 1.8279x over previous
//
#include <hip/hip_runtime.h>
#include <hip/hip_bf16.h>
#include <math.h>

#define B_ 2
#define N_ 1024
#define H_ 512
#define NH_ 8
#define HD_ 64
#define G_ 50
#define TAB_ 1024
constexpr float MAXD = 10.0f;

typedef __attribute__((ext_vector_type(8))) short short8;
typedef __attribute__((ext_vector_type(4))) float f32x4;

__device__ inline ushort f2bf(float v) {
  __hip_bfloat16 h = __float2bfloat16(v);
  return *(ushort*)&h;
}
__device__ inline float bf2f(ushort u) {
  unsigned x = ((unsigned)u) << 16;
  return __uint_as_float(x);
}
__device__ inline void gload_lds16(const ushort* g, ushort* l) {
  __builtin_amdgcn_global_load_lds(
      (const __attribute__((address_space(1))) void*)g,
      (__attribute__((address_space(3))) void*)l, 16, 0, 0);
}

// ---------------- fused prep: 3 weight transposes + bias table + LN1 ----------------
__device__ inline void transp_dev(const float* __restrict__ src,
                                  ushort* __restrict__ d, int R, int C,
                                  int bx, int by, int t, float (*tile)[33]) {
  int r0 = by * 32, c0 = bx * 32;
  int rr = t >> 5, cc = t & 31;
  #pragma unroll
  for (int p = 0; p < 4; ++p)
    tile[rr + p * 8][cc] = src[(size_t)(r0 + rr + p * 8) * C + c0 + cc];
  __syncthreads();
  #pragma unroll
  for (int p = 0; p < 4; ++p)
    d[(size_t)(c0 + rr + p * 8) * R + r0 + cc] = f2bf(tile[cc][rr + p * 8]);
}

__global__ __launch_bounds__(256) void prep_k(
    const float* wq, const float* wk, const float* wv, const float* wo,
    const float* w1, const float* w2, ushort* __restrict__ wT4,
    ushort* __restrict__ w1T, ushort* __restrict__ w2T,
    const float* __restrict__ widths, const float* __restrict__ dp_w,
    const float* __restrict__ dp_b, float2* __restrict__ tab2,
    const float* __restrict__ x, const float* __restrict__ ln1g,
    const float* __restrict__ ln1b, ushort* __restrict__ xn) {
  __shared__ float tile[32][33];
  __shared__ float red2[4][2];
  int bid = blockIdx.x, t = threadIdx.x;
  if (bid < 1024) {
    int z = bid >> 8, rem = bid & 255;
    const float* src = (z == 0) ? wq : (z == 1) ? wk : (z == 2) ? wv : wo;
    transp_dev(src, wT4 + (size_t)z * 512 * 512, 512, 512, rem & 15, rem >> 4, t, tile);
  } else if (bid < 2048) {
    int rem = bid - 1024;
    transp_dev(w1, w1T, 512, 2048, rem & 63, rem >> 6, t, tile);
  } else if (bid < 3072) {
    int rem = bid - 2048;
    transp_dev(w2, w2T, 2048, 512, rem & 15, rem >> 4, t, tile);
  } else if (bid < 3105) {
    int i = (bid - 3072) * 256 + t;
    if (i >= NH_ * (TAB_ + 1)) return;
    int h = i / (TAB_ + 1), tt = i % (TAB_ + 1);
    int t1 = tt < TAB_ ? tt + 1 : tt;
    float d0 = (float)tt * (MAXD / TAB_);
    float d1 = (float)t1 * (MAXD / TAB_);
    float v0 = dp_b[h], v1 = dp_b[h];
    for (int g = 0; g < G_; ++g) {
      float c = (float)g * (MAXD / 49.0f);
      float w = widths[g];
      float inv = -1.0f / (2.0f * w * w);
      float wg = dp_w[g * NH_ + h];
      float e0 = d0 - c, e1 = d1 - c;
      v0 += expf(e0 * e0 * inv) * wg;
      v1 += expf(e1 * e1 * inv) * wg;
    }
    tab2[i] = make_float2(v0, v1);
  } else {
    // LN1: 2 rows per block (128 threads each)
    int row = (bid - 3105) * 2 + (t >> 7);
    int tl = t & 127;
    float4 v = *(const float4*)(x + (size_t)row * H_ + tl * 4);
    float s = v.x + v.y + v.z + v.w;
    float sq = v.x * v.x + v.y * v.y + v.z * v.z + v.w * v.w;
    #pragma unroll
    for (int m = 1; m < 64; m <<= 1) {
      s += __shfl_xor(s, m, 64);
      sq += __shfl_xor(sq, m, 64);
    }
    int wid = t >> 6;
    if ((t & 63) == 0) { red2[wid][0] = s; red2[wid][1] = sq; }
    __syncthreads();
    int rw = (t >> 7) * 2;
    s = red2[rw][0] + red2[rw + 1][0];
    sq = red2[rw][1] + red2[rw + 1][1];
    float mu = s * (1.0f / H_);
    float var = sq * (1.0f / H_) - mu * mu;
    float rs = rsqrtf(var + 1e-5f);
    float4 gg = *(const float4*)(ln1g + tl * 4);
    float4 bb = *(const float4*)(ln1b + tl * 4);
    ushort4 o;
    o.x = f2bf((v.x - mu) * rs * gg.x + bb.x);
    o.y = f2bf((v.y - mu) * rs * gg.y + bb.y);
    o.z = f2bf((v.z - mu) * rs * gg.z + bb.z);
    o.w = f2bf((v.w - mu) * rs * gg.w + bb.w);
    *(ushort4*)(xn + (size_t)row * H_ + tl * 4) = o;
  }
}

// ---------------- bf16 MFMA GEMM, global_load_lds 2-phase double-buffer ----------
enum { EPI_QKV = 1, EPI_RES = 2, EPI_GELU = 3, EPI_PART = 4 };

template <int BM, int BN, int EPI>
__global__ __launch_bounds__(256) void mfma_gemm(const ushort* __restrict__ A,
                                                 const ushort* __restrict__ Bt,
                                                 const float* __restrict__ b0,
                                                 const float* __restrict__ b1,
                                                 const float* __restrict__ b2,
                                                 const float* __restrict__ resid,
                                                 void* __restrict__ outv,
                                                 int K, int Ks, int Nc) {
  __shared__ ushort As[2][BM * 32];
  __shared__ ushort Bs[2][BN * 32];
  int t = threadIdx.x;
  int z = blockIdx.z;
  const ushort* Bz = Bt + (size_t)z * Nc * Ks;
  const float* bias = (z == 0) ? b0 : (z == 1) ? b1 : b2;
  int m0 = blockIdx.y * BM, n0 = blockIdx.x * BN;
  int lane = t & 63, w = t >> 6, wr = w >> 1, wc = w & 1;
  int lrow = lane & 15, lkg = lane >> 4;
  constexpr int NFM = BM / 32, NFN = BN / 32;
  constexpr int AL = BM / 64, BL = BN / 64;
  f32x4 acc[NFM][NFN] = {};
  int rl = lane >> 2, kgl = lane & 3;

  auto stage = [&](int buf, int kt) {
    #pragma unroll
    for (int p = 0; p < AL; ++p) {
      int r = w * (BM / 4) + p * 16 + rl;
      int kgs = kgl ^ (r & 3);
      gload_lds16(&A[(size_t)(m0 + r) * Ks + kt + kgs * 8],
                  &As[buf][(w * (BM / 4) + p * 16) * 32]);
    }
    #pragma unroll
    for (int p = 0; p < BL; ++p) {
      int r = w * (BN / 4) + p * 16 + rl;
      int kgs = kgl ^ (r & 3);
      gload_lds16(&Bz[(size_t)(n0 + r) * Ks + kt + kgs * 8],
                  &Bs[buf][(w * (BN / 4) + p * 16) * 32]);
    }
  };
  auto compute = [&](int buf) {
    short8 af[NFM], bfr[NFN];
    #pragma unroll
    for (int fm = 0; fm < NFM; ++fm) {
      int r = wr * (BM / 2) + fm * 16 + lrow;
      af[fm] = *(const short8*)&As[buf][r * 32 + ((lkg ^ (r & 3)) << 3)];
    }
    #pragma unroll
    for (int fn = 0; fn < NFN; ++fn) {
      int r = wc * (BN / 2) + fn * 16 + lrow;
      bfr[fn] = *(const short8*)&Bs[buf][r * 32 + ((lkg ^ (r & 3)) << 3)];
    }
    #pragma unroll
    for (int fm = 0; fm < NFM; ++fm)
      #pragma unroll
      for (int fn = 0; fn < NFN; ++fn)
        acc[fm][fn] = __builtin_amdgcn_mfma_f32_16x16x32_bf16(af[fm], bfr[fn],
                                                              acc[fm][fn], 0, 0, 0);
  };

  stage(0, 0);
  __syncthreads();
  int cur = 0;
  for (int kt = 0; kt < K; kt += 32) {
    if (kt + 32 < K) stage(cur ^ 1, kt + 32);
    compute(cur);
    __syncthreads();
    cur ^= 1;
  }

  int rbase = (lane >> 4) * 4;
  if constexpr (EPI == EPI_QKV) {
    if (z < 2) {
      #pragma unroll
      for (int fm = 0; fm < NFM; ++fm)
        #pragma unroll
        for (int fn = 0; fn < NFN; ++fn)
          #pragma unroll
          for (int j = 0; j < 4; ++j) {
            int row = m0 + wr * (BM / 2) + fm * 16 + rbase + j;
            int col = n0 + wc * (BN / 2) + fn * 16 + lrow;
            float v = acc[fm][fn][j] + bias[col];
            ushort* q = (ushort*)outv + (size_t)z * (1 << 20);
            int bb = row >> 10, n = row & (N_ - 1);
            int h = col >> 6, d = col & 63;
            q[(((size_t)(bb * NH_ + h)) * N_ + n) * HD_ + d] = f2bf(v);
          }
    } else {
      // V: transpose via LDS, write coalesced 32B/thread lines along n
      __shared__ float vtile[64 * 65];
      #pragma unroll
      for (int fm = 0; fm < NFM; ++fm)
        #pragma unroll
        for (int fn = 0; fn < NFN; ++fn)
          #pragma unroll
          for (int j = 0; j < 4; ++j) {
            int rloc = wr * (BM / 2) + fm * 16 + rbase + j;
            int cloc = wc * (BN / 2) + fn * 16 + lrow;
            vtile[rloc * 65 + cloc] = acc[fm][fn][j] + bias[n0 + cloc];
          }
      __syncthreads();
      int d_ = t & 63, nc = t >> 6;
      int h = n0 >> 6;
      int bb = m0 >> 10, nbase = m0 & (N_ - 1);
      ushort* dst = (ushort*)outv + (size_t)2 * (1 << 20) +
                    (((size_t)(bb * NH_ + h)) * HD_ + d_) * N_ + nbase + nc * 16;
      short8 o0, o1;
      #pragma unroll
      for (int i = 0; i < 8; ++i) {
        o0[i] = (short)f2bf(vtile[(nc * 16 + i) * 65 + d_]);
        o1[i] = (short)f2bf(vtile[(nc * 16 + 8 + i) * 65 + d_]);
      }
      *(short8*)&dst[0] = o0;
      *(short8*)&dst[8] = o1;
    }
  } else {
    #pragma unroll
    for (int fm = 0; fm < NFM; ++fm) {
      #pragma unroll
      for (int fn = 0; fn < NFN; ++fn) {
        #pragma unroll
        for (int j = 0; j < 4; ++j) {
          int row = m0 + wr * (BM / 2) + fm * 16 + rbase + j;
          int col = n0 + wc * (BN / 2) + fn * 16 + lrow;
          float v = acc[fm][fn][j] + bias[col];
          if constexpr (EPI == EPI_RES) {
            ((float*)outv)[(size_t)row * Nc + col] =
                resid[(size_t)row * Nc + col] + v;
          } else {  // GELU -> bf16
            ((ushort*)outv)[(size_t)row * Nc + col] =
                f2bf(0.5f * v * (1.0f + erff(v * 0.70710678118654752f)));
          }
        }
      }
    }
  }
}

// ---------------- 512-thread GEMM, in-block K-split x2 + LDS reduce ----------
template <int EPI>
__global__ __launch_bounds__(512) void mfma_gemm2(const ushort* __restrict__ A,
                                                  const ushort* __restrict__ Bt,
                                                  const float* __restrict__ bias,
                                                  const float* __restrict__ resid,
                                                  void* __restrict__ outv,
                                                  int K, int Ks, int Nc) {
  constexpr int BM = 64, BN = 64;
  __shared__ ushort AsBs[2][2][2][BM * 32];  // [A/B][half][buf]
  int t = threadIdx.x;
  int half = t >> 8;
  int lane = t & 63;
  int wl = (t >> 6) & 3;  // wave within half
  int wr = wl >> 1, wc = wl & 1;
  int lrow = lane & 15, lkg = lane >> 4;
  int k0 = half * K;
  int m0 = blockIdx.y * BM, n0 = blockIdx.x * BN;
  f32x4 acc[2][2] = {};
  int rl = lane >> 2, kgl = lane & 3;

  auto stage = [&](int buf, int kt) {
    int r = wl * 16 + rl;
    int kgs = kgl ^ (r & 3);
    gload_lds16(&A[(size_t)(m0 + r) * Ks + k0 + kt + kgs * 8],
                &AsBs[0][half][buf][(wl * 16) * 32]);
    gload_lds16(&Bt[(size_t)(n0 + r) * Ks + k0 + kt + kgs * 8],
                &AsBs[1][half][buf][(wl * 16) * 32]);
  };
  auto compute = [&](int buf) {
    short8 af[2], bfr[2];
    #pragma unroll
    for (int fm = 0; fm < 2; ++fm) {
      int r = wr * 32 + fm * 16 + lrow;
      af[fm] = *(const short8*)&AsBs[0][half][buf][r * 32 + ((lkg ^ (r & 3)) << 3)];
    }
    #pragma unroll
    for (int fn = 0; fn < 2; ++fn) {
      int r = wc * 32 + fn * 16 + lrow;
      bfr[fn] = *(const short8*)&AsBs[1][half][buf][r * 32 + ((lkg ^ (r & 3)) << 3)];
    }
    #pragma unroll
    for (int fm = 0; fm < 2; ++fm)
      #pragma unroll
      for (int fn = 0; fn < 2; ++fn)
        acc[fm][fn] = __builtin_amdgcn_mfma_f32_16x16x32_bf16(af[fm], bfr[fn],
                                                              acc[fm][fn], 0, 0, 0);
  };

  stage(0, 0);
  __syncthreads();
  int cur = 0;
  for (int kt = 0; kt < K; kt += 32) {
    if (kt + 32 < K) stage(cur ^ 1, kt + 32);
    compute(cur);
    __syncthreads();
    cur ^= 1;
  }

  // cross-half reduce via LDS (aliases AsBs; all LDS reads drained by last barrier)
  float* red = (float*)&AsBs[0][0][0][0];  // 64*65 f32 = 16.6 KB of 32 KB
  int rbase = (lane >> 4) * 4;
  if (half == 1) {
    #pragma unroll
    for (int fm = 0; fm < 2; ++fm)
      #pragma unroll
      for (int fn = 0; fn < 2; ++fn)
        #pragma unroll
        for (int j = 0; j < 4; ++j) {
          int rloc = wr * 32 + fm * 16 + rbase + j;
          int cloc = wc * 32 + fn * 16 + lrow;
          red[rloc * 65 + cloc] = acc[fm][fn][j];
        }
  }
  __syncthreads();
  if (half == 0) {
    #pragma unroll
    for (int fm = 0; fm < 2; ++fm)
      #pragma unroll
      for (int fn = 0; fn < 2; ++fn)
        #pragma unroll
        for (int j = 0; j < 4; ++j) {
          int rloc = wr * 32 + fm * 16 + rbase + j;
          int cloc = wc * 32 + fn * 16 + lrow;
          float sum = acc[fm][fn][j] + red[rloc * 65 + cloc];
          int row = m0 + rloc, col = n0 + cloc;
          if constexpr (EPI == EPI_PART) {
            ((float*)outv)[(size_t)row * Nc + col] = sum;
          } else {  // EPI_RES
            ((float*)outv)[(size_t)row * Nc + col] =
                resid[(size_t)row * Nc + col] + sum + bias[col];
          }
        }
  }
}

// ---------------- fused K-split combine + LayerNorm (x1 f32 + xn bf16) ----------
__global__ __launch_bounds__(128) void comb2ln_k(const float* __restrict__ p,
                                                 const float* __restrict__ resid,
                                                 const float* __restrict__ bias,
                                                 const float* __restrict__ g,
                                                 const float* __restrict__ bl,
                                                 float* __restrict__ x1out,
                                                 ushort* __restrict__ xnout) {
  int row = blockIdx.x, t = threadIdx.x;
  int base = row * H_ + t * 4;
  f32x4 a = *(const f32x4*)&p[base];
  f32x4 r = *(const f32x4*)&resid[base];
  f32x4 bi = *(const f32x4*)&bias[t * 4];
  f32x4 v = r + a + bi;
  *(f32x4*)&x1out[base] = v;
  float s = v[0] + v[1] + v[2] + v[3];
  float sq = v[0] * v[0] + v[1] * v[1] + v[2] * v[2] + v[3] * v[3];
  #pragma unroll
  for (int m = 1; m < 64; m <<= 1) {
    s += __shfl_xor(s, m, 64);
    sq += __shfl_xor(sq, m, 64);
  }
  __shared__ float red[2][2];
  int wid = t >> 6;
  if ((t & 63) == 0) { red[wid][0] = s; red[wid][1] = sq; }
  __syncthreads();
  s = red[0][0] + red[1][0];
  sq = red[0][1] + red[1][1];
  float mu = s * (1.0f / H_);
  float var = sq * (1.0f / H_) - mu * mu;
  float rs = rsqrtf(var + 1e-5f);
  float4 gg = *(const float4*)(g + t * 4);
  float4 bb = *(const float4*)(bl + t * 4);
  ushort4 o;
  o.x = f2bf((v[0] - mu) * rs * gg.x + bb.x);
  o.y = f2bf((v[1] - mu) * rs * gg.y + bb.y);
  o.z = f2bf((v[2] - mu) * rs * gg.z + bb.z);
  o.w = f2bf((v[3] - mu) * rs * gg.w + bb.w);
  *(ushort4*)(xnout + (size_t)row * H_ + t * 4) = o;
}

// ---------------- MFMA flash attention, j-split, dbuf LDS, reg-resident bias ----
constexpr int QT = 64, KT = 64, NJH = 2, NTH = N_ / (KT * NJH);  // 8 tiles/block
constexpr int JH = N_ / NJH;  // 512

__global__ __launch_bounds__(256) void attn_k(
    const ushort* __restrict__ q, const ushort* __restrict__ k,
    const ushort* __restrict__ v, const float* __restrict__ dist,
    const int* __restrict__ mask, const float2* __restrict__ tab2g,
    float* __restrict__ Op, float2* __restrict__ ml) {
  int qt = blockIdx.x, h = blockIdx.y, z = blockIdx.z;
  int b = z >> 1, jh = z & 1;
  int i0 = qt * QT;
  int jbase = jh * JH;
  __shared__ ushort Ks[2][KT * 64];  // [j][d], chunk ^= (j&7)
  __shared__ ushort Vt[2][64 * KT];  // [d][j], chunk ^= (d&7)
  __shared__ ushort Ps[4][16 * 64];  // per-warp P [q][j], chunk ^= (q&7)
  __shared__ float2 tl2[TAB_ + 1];
  __shared__ float mfl[JH];
  int t = threadIdx.x;
  int lane = t & 63, w = t >> 6;
  int l = lane & 15, g = lane >> 4;

  for (int i = t; i <= TAB_; i += 256) tl2[i] = tab2g[h * (TAB_ + 1) + i];
  for (int i = t; i < JH; i += 256) mfl[i] = (mask[b * N_ + jbase + i] == 0) ? -1e9f : 0.0f;

  const size_t ho = ((size_t)(b * NH_ + h)) * N_ * HD_;
  const ushort* qb = q + ho;
  const ushort* kb = k + ho;
  const ushort* vb = v + ho;  // V^T layout: [d][N_]

  int qloc = w * 16 + 4 * g;
  int qrow = i0 + w * 16 + l;
  short8 qf[2];
  qf[0] = *(const short8*)&qb[(size_t)qrow * 64 + g * 8];
  qf[1] = *(const short8*)&qb[(size_t)qrow * 64 + 32 + g * 8];

  int c2 = t & 7, jr = t >> 3;  // K/V staging: chunk 0..7, row 0..31 (+32)

  auto stK = [&](int buf, short8 val, int j2) {
    *(short8*)&Ks[buf][j2 * 64 + ((c2 ^ (j2 & 7)) << 3)] = val;
  };
  auto stV = [&](int buf, short8 val, int d) {
    *(short8*)&Vt[buf][d * 64 + ((c2 ^ (d & 7)) << 3)] = val;
  };

  // dist in MFMA S-layout: row = i0+qloc+reg, col = jbase + tt*KT + fj*16 + l
  const float* dbase = dist + ((size_t)b * N_ + (i0 + qloc)) * N_ + jbase + l;

  // --- prologue: load + stage tile 0 ---
  short8 k0a, k1a, v0a, v1a;
  float ddc[4][4], ddn[4][4];
  {
    const ushort* kn = kb + (size_t)jbase * 64;
    const ushort* vn = vb + jbase;
    k0a = *(const short8*)&kn[(size_t)jr * 64 + c2 * 8];
    k1a = *(const short8*)&kn[(size_t)(jr + 32) * 64 + c2 * 8];
    v0a = *(const short8*)&vn[(size_t)jr * N_ + c2 * 8];
    v1a = *(const short8*)&vn[(size_t)(jr + 32) * N_ + c2 * 8];
    #pragma unroll
    for (int reg = 0; reg < 4; ++reg)
      #pragma unroll
      for (int fj = 0; fj < 4; ++fj)
        ddc[reg][fj] = dbase[(size_t)reg * N_ + fj * 16];
  }
  __syncthreads();  // tl2 + mfl ready
  stK(0, k0a, jr); stK(0, k1a, jr + 32);
  stV(0, v0a, jr); stV(0, v1a, jr + 32);
  __syncthreads();

  float m_[4] = {-1e30f, -1e30f, -1e30f, -1e30f};
  float l_[4] = {0.f, 0.f, 0.f, 0.f};
  f32x4 acc[4] = {{0,0,0,0},{0,0,0,0},{0,0,0,0},{0,0,0,0}};

  int cur = 0;
  for (int tt = 0; tt < NTH; ++tt) {
    const int j0 = jbase + tt * KT;
    if (tt + 1 < NTH) {
      const ushort* kn = kb + (size_t)(j0 + KT) * 64;
      const ushort* vn = vb + (j0 + KT);
      k0a = *(const short8*)&kn[(size_t)jr * 64 + c2 * 8];
      k1a = *(const short8*)&kn[(size_t)(jr + 32) * 64 + c2 * 8];
      v0a = *(const short8*)&vn[(size_t)jr * N_ + c2 * 8];
      v1a = *(const short8*)&vn[(size_t)(jr + 32) * N_ + c2 * 8];
      #pragma unroll
      for (int reg = 0; reg < 4; ++reg)
        #pragma unroll
        for (int fj = 0; fj < 4; ++fj)
          ddn[reg][fj] = dbase[(size_t)reg * N_ + (tt + 1) * KT + fj * 16];
    }
    // S = Q K^T
    f32x4 sa[4] = {{0,0,0,0},{0,0,0,0},{0,0,0,0},{0,0,0,0}};
    __builtin_amdgcn_s_setprio(1);
    #pragma unroll
    for (int dblk = 0; dblk < 2; ++dblk)
      #pragma unroll
      for (int fj = 0; fj < 4; ++fj) {
        int j2 = fj * 16 + l;
        short8 kf = *(const short8*)&Ks[cur][j2 * 64 + (((dblk * 4 + g) ^ (j2 & 7)) << 3)];
        sa[fj] = __builtin_amdgcn_mfma_f32_16x16x32_bf16(qf[dblk], kf, sa[fj], 0, 0, 0);
      }
    __builtin_amdgcn_s_setprio(0);
    // softmax: bias = table-lerp(dist in regs) + mask
    float al_[4];
    #pragma unroll
    for (int reg = 0; reg < 4; ++reg) {
      float svr[4];
      #pragma unroll
      for (int fj = 0; fj < 4; ++fj) {
        float u = ddc[reg][fj] * ((float)TAB_ / MAXD);
        int it = (int)u;
        it = it < 0 ? 0 : (it > TAB_ - 1 ? TAB_ - 1 : it);
        float f = u - (float)it;
        float2 tv = tl2[it];
        float bias = tv.x + f * (tv.y - tv.x) + mfl[tt * KT + fj * 16 + l];
        svr[fj] = fmaf(sa[fj][reg], 0.125f, bias);
      }
      float rm = fmaxf(fmaxf(svr[0], svr[1]), fmaxf(svr[2], svr[3]));
      rm = fmaxf(rm, __shfl_xor(rm, 1, 64));
      rm = fmaxf(rm, __shfl_xor(rm, 2, 64));
      rm = fmaxf(rm, __shfl_xor(rm, 4, 64));
      rm = fmaxf(rm, __shfl_xor(rm, 8, 64));
      float mn = fmaxf(m_[reg], rm);
      float al = __expf(m_[reg] - mn);
      m_[reg] = mn;
      al_[reg] = al;
      float ps = 0.f;
      int qlq = 4 * g + reg;
      #pragma unroll
      for (int fj = 0; fj < 4; ++fj) {
        float p = __expf(svr[fj] - mn);
        ps += p;
        int c = fj * 2 + (l >> 3);
        Ps[w][qlq * 64 + ((c ^ (qlq & 7)) << 3) + (l & 7)] = f2bf(p);
      }
      ps += __shfl_xor(ps, 1, 64);
      ps += __shfl_xor(ps, 2, 64);
      ps += __shfl_xor(ps, 4, 64);
      ps += __shfl_xor(ps, 8, 64);
      l_[reg] = l_[reg] * al + ps;
    }
    #pragma unroll
    for (int fd = 0; fd < 4; ++fd)
      #pragma unroll
      for (int reg = 0; reg < 4; ++reg) acc[fd][reg] *= al_[reg];
    // O += P V   (P A-frags, V^T B-frags)
    __builtin_amdgcn_s_setprio(1);
    #pragma unroll
    for (int jj = 0; jj < 2; ++jj) {
      short8 pa = *(const short8*)&Ps[w][l * 64 + (((jj * 4 + g) ^ (l & 7)) << 3)];
      #pragma unroll
      for (int fd = 0; fd < 4; ++fd) {
        int d2 = fd * 16 + l;
        short8 vf = *(const short8*)&Vt[cur][d2 * 64 + (((jj * 4 + g) ^ (d2 & 7)) << 3)];
        acc[fd] = __builtin_amdgcn_mfma_f32_16x16x32_bf16(pa, vf, acc[fd], 0, 0, 0);
      }
    }
    __builtin_amdgcn_s_setprio(0);
    // stage tile tt+1 into the other buffer (no race: readers use buf cur)
    if (tt + 1 < NTH) {
      int nb = cur ^ 1;
      stK(nb, k0a, jr); stK(nb, k1a, jr + 32);
      stV(nb, v0a, jr); stV(nb, v1a, jr + 32);
      #pragma unroll
      for (int reg = 0; reg < 4; ++reg)
        #pragma unroll
        for (int fj = 0; fj < 4; ++fj) ddc[reg][fj] = ddn[reg][fj];
    }
    __syncthreads();
    cur ^= 1;
  }
  // epilogue: unnormalized partials + (m,l)
  const size_t pbase = (((size_t)(b * NJH + jh) * NH_ + h) * N_) + i0;
  #pragma unroll
  for (int reg = 0; reg < 4; ++reg) {
    int rowl = w * 16 + 4 * g + reg;
    float* op = Op + (pbase + rowl) * HD_ + l;
    #pragma unroll
    for (int fd = 0; fd < 4; ++fd) op[fd * 16] = acc[fd][reg];
    if (l == 0) ml[pbase + rowl] = make_float2(m_[reg], l_[reg]);
  }
}

// ---------------- combine j-split partials ----------------
__global__ __launch_bounds__(256) void comb_k(const float* __restrict__ Op,
                                              const float2* __restrict__ ml,
                                              ushort* __restrict__ ao) {
  int idx = blockIdx.x * 256 + threadIdx.x;
  int row = idx >> 4;
  int dq = (idx & 15) * 4;
  int b = row >> 13, h = (row >> 10) & 7, n = row & 1023;
  size_t p0 = (((size_t)(b * NJH + 0) * NH_ + h) * N_) + n;
  size_t p1 = (((size_t)(b * NJH + 1) * NH_ + h) * N_) + n;
  float2 v0 = ml[p0], v1 = ml[p1];
  float M = fmaxf(v0.x, v1.x);
  float a0 = __expf(v0.x - M), a1 = __expf(v1.x - M);
  float inv = 1.0f / (v0.y * a0 + v1.y * a1);
  float4 O0 = *(const float4*)&Op[p0 * HD_ + dq];
  float4 O1 = *(const float4*)&Op[p1 * HD_ + dq];
  ushort4 o;
  o.x = f2bf((O0.x * a0 + O1.x * a1) * inv);
  o.y = f2bf((O0.y * a0 + O1.y * a1) * inv);
  o.z = f2bf((O0.z * a0 + O1.z * a1) * inv);
  o.w = f2bf((O0.w * a0 + O1.w * a1) * inv);
  *(ushort4*)&ao[((size_t)(b * N_ + n)) * H_ + h * HD_ + dq] = o;
}

extern "C" void kernel_launch(void* const* d_in, const int* in_sizes, int n_in,
                              void* d_out, int out_size, void* d_ws, size_t ws_size,
                              hipStream_t stream) {
  const float* x = (const float*)d_in[0];
  const float* distances = (const float*)d_in[1];
  const int* mask = (const int*)d_in[2];
  const float* widths = (const float*)d_in[3];
  const float* dp_w = (const float*)d_in[4];
  const float* dp_b = (const float*)d_in[5];
  const float* wq = (const float*)d_in[6];
  const float* bq = (const float*)d_in[7];
  const float* wk = (const float*)d_in[8];
  const float* bk = (const float*)d_in[9];
  const float* wv = (const float*)d_in[10];
  const float* bv = (const float*)d_in[11];
  const float* wo = (const float*)d_in[12];
  const float* bo = (const float*)d_in[13];
  const float* ln1_g = (const float*)d_in[14];
  const float* ln1_b = (const float*)d_in[15];
  const float* ln2_g = (const float*)d_in[16];
  const float* ln2_b = (const float*)d_in[17];
  const float* w1 = (const float*)d_in[18];
  const float* b1 = (const float*)d_in[19];
  const float* w2 = (const float*)d_in[20];
  const float* b2 = (const float*)d_in[21];
  float* out = (float*)d_out;
  float* wsf = (float*)d_ws;

  const size_t M1 = (size_t)1 << 20;
  ushort* qkvb = (ushort*)wsf;                       // 3M bf16 (V transposed)
  float* x1 = wsf + 2 * M1;                          // 1M f32
  ushort* hbuf = (ushort*)(wsf + 3 * M1);            // 4M bf16
  ushort* xn = (ushort*)(wsf + 5 * M1);              // 1M bf16
  ushort* xn2 = (ushort*)(wsf + 5 * M1 + M1 / 2);
  ushort* ao = (ushort*)(wsf + 6 * M1);              // 1M bf16
  ushort* wT4 = (ushort*)(wsf + 6 * M1 + M1 / 2);    // 4x 512x512 bf16
  ushort* w1T = (ushort*)(wsf + 7 * M1);             // [2048][512] bf16
  ushort* w2T = (ushort*)(wsf + 7 * M1 + M1 / 2);    // [512][2048] bf16
  float2* tab2 = (float2*)(wsf + 8 * M1);            // 8200 float2
  float* Op = wsf + 9 * M1;                          // 2M f32 attn partials
  float2* ml = (float2*)(wsf + 11 * M1);             // 32K float2
  float* pAO = wsf + 12 * M1;                        // 1M f32 O-proj partial

  prep_k<<<4129, 256, 0, stream>>>(wq, wk, wv, wo, w1, w2, wT4, w1T, w2T,
                                   widths, dp_w, dp_b, tab2, x, ln1_g, ln1_b, xn);

  mfma_gemm<64, 64, EPI_QKV><<<dim3(8, 32, 3), 256, 0, stream>>>(
      xn, wT4, bq, bk, bv, nullptr, qkvb, 512, 512, 512);

  attn_k<<<dim3(N_ / QT, NH_, B_ * NJH), 256, 0, stream>>>(
      qkvb, qkvb + M1, qkvb + 2 * M1, distances, mask, tab2, Op, ml);
  comb_k<<<1024, 256, 0, stream>>>(Op, ml, ao);

  // attn-O projection: in-block K-split x2, single partial; fused combine+LN2
  mfma_gemm2<EPI_PART><<<dim3(8, 32), 512, 0, stream>>>(
      ao, wT4 + (size_t)3 * 512 * 512, bo, nullptr, pAO, 256, 512, 512);
  comb2ln_k<<<B_ * N_, 128, 0, stream>>>(pAO, x, bo, ln2_g, ln2_b, x1, xn2);

  // FFN1: 128x64 tiles -> 512 blocks (2/CU)
  mfma_gemm<128, 64, EPI_GELU><<<dim3(32, 16, 1), 256, 0, stream>>>(
      xn2, w1T, b1, b1, b1, nullptr, hbuf, 512, 512, 2048);

  // FFN2: in-block K-split x2, fully fused epilogue (resid + bias -> out)
  mfma_gemm2<EPI_RES><<<dim3(8, 32), 512, 0, stream>>>(
      hbuf, w2T, b2, x1, out, 1024, 2048, 512);
}

// Round 19
// 96.682 us; speedup vs baseline: 1.8666x; 1.0212x over previous
//
#include <hip/hip_runtime.h>
#include <hip/hip_bf16.h>
#include <math.h>

#define B_ 2
#define N_ 1024
#define H_ 512
#define NH_ 8
#define HD_ 64
#define G_ 50
#define TAB_ 1024
constexpr float MAXD = 10.0f;

typedef __attribute__((ext_vector_type(8))) short short8;
typedef __attribute__((ext_vector_type(4))) float f32x4;

__device__ inline ushort f2bf(float v) {
  __hip_bfloat16 h = __float2bfloat16(v);
  return *(ushort*)&h;
}
__device__ inline float bf2f(ushort u) {
  unsigned x = ((unsigned)u) << 16;
  return __uint_as_float(x);
}
__device__ inline void gload_lds16(const ushort* g, ushort* l) {
  __builtin_amdgcn_global_load_lds(
      (const __attribute__((address_space(1))) void*)g,
      (__attribute__((address_space(3))) void*)l, 16, 0, 0);
}

// ---------------- fused prep: 3 weight transposes + bias table + LN1 ----------------
__device__ inline void transp_dev(const float* __restrict__ src,
                                  ushort* __restrict__ d, int R, int C,
                                  int bx, int by, int t, float (*tile)[33]) {
  int r0 = by * 32, c0 = bx * 32;
  int rr = t >> 5, cc = t & 31;
  #pragma unroll
  for (int p = 0; p < 4; ++p)
    tile[rr + p * 8][cc] = src[(size_t)(r0 + rr + p * 8) * C + c0 + cc];
  __syncthreads();
  #pragma unroll
  for (int p = 0; p < 4; ++p)
    d[(size_t)(c0 + rr + p * 8) * R + r0 + cc] = f2bf(tile[cc][rr + p * 8]);
}

__global__ __launch_bounds__(256) void prep_k(
    const float* wq, const float* wk, const float* wv, const float* wo,
    const float* w1, const float* w2, ushort* __restrict__ wT4,
    ushort* __restrict__ w1T, ushort* __restrict__ w2T,
    const float* __restrict__ widths, const float* __restrict__ dp_w,
    const float* __restrict__ dp_b, float2* __restrict__ tab2,
    const float* __restrict__ x, const float* __restrict__ ln1g,
    const float* __restrict__ ln1b, ushort* __restrict__ xn) {
  __shared__ float tile[32][33];
  __shared__ float red2[4][2];
  int bid = blockIdx.x, t = threadIdx.x;
  if (bid < 1024) {
    int z = bid >> 8, rem = bid & 255;
    const float* src = (z == 0) ? wq : (z == 1) ? wk : (z == 2) ? wv : wo;
    transp_dev(src, wT4 + (size_t)z * 512 * 512, 512, 512, rem & 15, rem >> 4, t, tile);
  } else if (bid < 2048) {
    int rem = bid - 1024;
    transp_dev(w1, w1T, 512, 2048, rem & 63, rem >> 6, t, tile);
  } else if (bid < 3072) {
    int rem = bid - 2048;
    transp_dev(w2, w2T, 2048, 512, rem & 15, rem >> 4, t, tile);
  } else if (bid < 3105) {
    int i = (bid - 3072) * 256 + t;
    if (i >= NH_ * (TAB_ + 1)) return;
    int h = i / (TAB_ + 1), tt = i % (TAB_ + 1);
    int t1 = tt < TAB_ ? tt + 1 : tt;
    float d0 = (float)tt * (MAXD / TAB_);
    float d1 = (float)t1 * (MAXD / TAB_);
    float v0 = dp_b[h], v1 = dp_b[h];
    for (int g = 0; g < G_; ++g) {
      float c = (float)g * (MAXD / 49.0f);
      float w = widths[g];
      float inv = -1.0f / (2.0f * w * w);
      float wg = dp_w[g * NH_ + h];
      float e0 = d0 - c, e1 = d1 - c;
      v0 += expf(e0 * e0 * inv) * wg;
      v1 += expf(e1 * e1 * inv) * wg;
    }
    tab2[i] = make_float2(v0, v1);
  } else {
    // LN1: 2 rows per block (128 threads each)
    int row = (bid - 3105) * 2 + (t >> 7);
    int tl = t & 127;
    float4 v = *(const float4*)(x + (size_t)row * H_ + tl * 4);
    float s = v.x + v.y + v.z + v.w;
    float sq = v.x * v.x + v.y * v.y + v.z * v.z + v.w * v.w;
    #pragma unroll
    for (int m = 1; m < 64; m <<= 1) {
      s += __shfl_xor(s, m, 64);
      sq += __shfl_xor(sq, m, 64);
    }
    int wid = t >> 6;
    if ((t & 63) == 0) { red2[wid][0] = s; red2[wid][1] = sq; }
    __syncthreads();
    int rw = (t >> 7) * 2;
    s = red2[rw][0] + red2[rw + 1][0];
    sq = red2[rw][1] + red2[rw + 1][1];
    float mu = s * (1.0f / H_);
    float var = sq * (1.0f / H_) - mu * mu;
    float rs = rsqrtf(var + 1e-5f);
    float4 gg = *(const float4*)(ln1g + tl * 4);
    float4 bb = *(const float4*)(ln1b + tl * 4);
    ushort4 o;
    o.x = f2bf((v.x - mu) * rs * gg.x + bb.x);
    o.y = f2bf((v.y - mu) * rs * gg.y + bb.y);
    o.z = f2bf((v.z - mu) * rs * gg.z + bb.z);
    o.w = f2bf((v.w - mu) * rs * gg.w + bb.w);
    *(ushort4*)(xn + (size_t)row * H_ + tl * 4) = o;
  }
}

// ---------------- bf16 MFMA GEMM, global_load_lds 2-phase double-buffer ----------
enum { EPI_QKV = 1, EPI_RES = 2, EPI_GELU = 3, EPI_PART = 4 };

template <int BM, int BN, int EPI>
__global__ __launch_bounds__(256) void mfma_gemm(const ushort* __restrict__ A,
                                                 const ushort* __restrict__ Bt,
                                                 const float* __restrict__ b0,
                                                 const float* __restrict__ b1,
                                                 const float* __restrict__ b2,
                                                 const float* __restrict__ resid,
                                                 void* __restrict__ outv,
                                                 int K, int Ks, int Nc) {
  __shared__ ushort As[2][BM * 32];
  __shared__ ushort Bs[2][BN * 32];
  int t = threadIdx.x;
  int z = blockIdx.z;
  const ushort* Bz = Bt + (size_t)z * Nc * Ks;
  const float* bias = (z == 0) ? b0 : (z == 1) ? b1 : b2;
  int m0 = blockIdx.y * BM, n0 = blockIdx.x * BN;
  int lane = t & 63, w = t >> 6, wr = w >> 1, wc = w & 1;
  int lrow = lane & 15, lkg = lane >> 4;
  constexpr int NFM = BM / 32, NFN = BN / 32;
  constexpr int AL = BM / 64, BL = BN / 64;
  f32x4 acc[NFM][NFN] = {};
  int rl = lane >> 2, kgl = lane & 3;

  auto stage = [&](int buf, int kt) {
    #pragma unroll
    for (int p = 0; p < AL; ++p) {
      int r = w * (BM / 4) + p * 16 + rl;
      int kgs = kgl ^ (r & 3);
      gload_lds16(&A[(size_t)(m0 + r) * Ks + kt + kgs * 8],
                  &As[buf][(w * (BM / 4) + p * 16) * 32]);
    }
    #pragma unroll
    for (int p = 0; p < BL; ++p) {
      int r = w * (BN / 4) + p * 16 + rl;
      int kgs = kgl ^ (r & 3);
      gload_lds16(&Bz[(size_t)(n0 + r) * Ks + kt + kgs * 8],
                  &Bs[buf][(w * (BN / 4) + p * 16) * 32]);
    }
  };
  auto compute = [&](int buf) {
    short8 af[NFM], bfr[NFN];
    #pragma unroll
    for (int fm = 0; fm < NFM; ++fm) {
      int r = wr * (BM / 2) + fm * 16 + lrow;
      af[fm] = *(const short8*)&As[buf][r * 32 + ((lkg ^ (r & 3)) << 3)];
    }
    #pragma unroll
    for (int fn = 0; fn < NFN; ++fn) {
      int r = wc * (BN / 2) + fn * 16 + lrow;
      bfr[fn] = *(const short8*)&Bs[buf][r * 32 + ((lkg ^ (r & 3)) << 3)];
    }
    #pragma unroll
    for (int fm = 0; fm < NFM; ++fm)
      #pragma unroll
      for (int fn = 0; fn < NFN; ++fn)
        acc[fm][fn] = __builtin_amdgcn_mfma_f32_16x16x32_bf16(af[fm], bfr[fn],
                                                              acc[fm][fn], 0, 0, 0);
  };

  stage(0, 0);
  __syncthreads();
  int cur = 0;
  for (int kt = 0; kt < K; kt += 32) {
    if (kt + 32 < K) stage(cur ^ 1, kt + 32);
    compute(cur);
    __syncthreads();
    cur ^= 1;
  }

  int rbase = (lane >> 4) * 4;
  if constexpr (EPI == EPI_QKV) {
    if (z < 2) {
      #pragma unroll
      for (int fm = 0; fm < NFM; ++fm)
        #pragma unroll
        for (int fn = 0; fn < NFN; ++fn)
          #pragma unroll
          for (int j = 0; j < 4; ++j) {
            int row = m0 + wr * (BM / 2) + fm * 16 + rbase + j;
            int col = n0 + wc * (BN / 2) + fn * 16 + lrow;
            float v = acc[fm][fn][j] + bias[col];
            ushort* q = (ushort*)outv + (size_t)z * (1 << 20);
            int bb = row >> 10, n = row & (N_ - 1);
            int h = col >> 6, d = col & 63;
            q[(((size_t)(bb * NH_ + h)) * N_ + n) * HD_ + d] = f2bf(v);
          }
    } else {
      // V: transpose via LDS, write coalesced 32B/thread lines along n
      __shared__ float vtile[64 * 65];
      #pragma unroll
      for (int fm = 0; fm < NFM; ++fm)
        #pragma unroll
        for (int fn = 0; fn < NFN; ++fn)
          #pragma unroll
          for (int j = 0; j < 4; ++j) {
            int rloc = wr * (BM / 2) + fm * 16 + rbase + j;
            int cloc = wc * (BN / 2) + fn * 16 + lrow;
            vtile[rloc * 65 + cloc] = acc[fm][fn][j] + bias[n0 + cloc];
          }
      __syncthreads();
      int d_ = t & 63, nc = t >> 6;
      int h = n0 >> 6;
      int bb = m0 >> 10, nbase = m0 & (N_ - 1);
      ushort* dst = (ushort*)outv + (size_t)2 * (1 << 20) +
                    (((size_t)(bb * NH_ + h)) * HD_ + d_) * N_ + nbase + nc * 16;
      short8 o0, o1;
      #pragma unroll
      for (int i = 0; i < 8; ++i) {
        o0[i] = (short)f2bf(vtile[(nc * 16 + i) * 65 + d_]);
        o1[i] = (short)f2bf(vtile[(nc * 16 + 8 + i) * 65 + d_]);
      }
      *(short8*)&dst[0] = o0;
      *(short8*)&dst[8] = o1;
    }
  } else {
    #pragma unroll
    for (int fm = 0; fm < NFM; ++fm) {
      #pragma unroll
      for (int fn = 0; fn < NFN; ++fn) {
        #pragma unroll
        for (int j = 0; j < 4; ++j) {
          int row = m0 + wr * (BM / 2) + fm * 16 + rbase + j;
          int col = n0 + wc * (BN / 2) + fn * 16 + lrow;
          float v = acc[fm][fn][j] + bias[col];
          if constexpr (EPI == EPI_RES) {
            ((float*)outv)[(size_t)row * Nc + col] =
                resid[(size_t)row * Nc + col] + v;
          } else {  // GELU -> bf16
            ((ushort*)outv)[(size_t)row * Nc + col] =
                f2bf(0.5f * v * (1.0f + erff(v * 0.70710678118654752f)));
          }
        }
      }
    }
  }
}

// ---------------- 512-thread GEMM, in-block K-split x2, K-chunk 64 ----------
// Grid is 1 block/CU, so LDS growth to 64KB is free; barrier count halves
// (one drain per 64-K instead of per 32-K) since no co-resident block hides it.
template <int EPI>
__global__ __launch_bounds__(512) void mfma_gemm2(const ushort* __restrict__ A,
                                                  const ushort* __restrict__ Bt,
                                                  const float* __restrict__ bias,
                                                  const float* __restrict__ resid,
                                                  void* __restrict__ outv,
                                                  int K, int Ks, int Nc) {
  constexpr int BM = 64, BN = 64;
  __shared__ ushort AsBs[2][2][2][2][BM * 32];  // [A/B][half][buf][sub]
  int t = threadIdx.x;
  int half = t >> 8;
  int lane = t & 63;
  int wl = (t >> 6) & 3;  // wave within half
  int wr = wl >> 1, wc = wl & 1;
  int lrow = lane & 15, lkg = lane >> 4;
  int k0 = half * K;
  int m0 = blockIdx.y * BM, n0 = blockIdx.x * BN;
  f32x4 acc[2][2] = {};
  int rl = lane >> 2, kgl = lane & 3;

  auto stage = [&](int buf, int kt) {
    int r = wl * 16 + rl;
    int kgs = kgl ^ (r & 3);
    #pragma unroll
    for (int sub = 0; sub < 2; ++sub) {
      int kk = k0 + kt + sub * 32;
      gload_lds16(&A[(size_t)(m0 + r) * Ks + kk + kgs * 8],
                  &AsBs[0][half][buf][sub][(wl * 16) * 32]);
      gload_lds16(&Bt[(size_t)(n0 + r) * Ks + kk + kgs * 8],
                  &AsBs[1][half][buf][sub][(wl * 16) * 32]);
    }
  };
  auto compute = [&](int buf) {
    #pragma unroll
    for (int sub = 0; sub < 2; ++sub) {
      short8 af[2], bfr[2];
      #pragma unroll
      for (int fm = 0; fm < 2; ++fm) {
        int r = wr * 32 + fm * 16 + lrow;
        af[fm] = *(const short8*)&AsBs[0][half][buf][sub][r * 32 + ((lkg ^ (r & 3)) << 3)];
      }
      #pragma unroll
      for (int fn = 0; fn < 2; ++fn) {
        int r = wc * 32 + fn * 16 + lrow;
        bfr[fn] = *(const short8*)&AsBs[1][half][buf][sub][r * 32 + ((lkg ^ (r & 3)) << 3)];
      }
      #pragma unroll
      for (int fm = 0; fm < 2; ++fm)
        #pragma unroll
        for (int fn = 0; fn < 2; ++fn)
          acc[fm][fn] = __builtin_amdgcn_mfma_f32_16x16x32_bf16(af[fm], bfr[fn],
                                                                acc[fm][fn], 0, 0, 0);
    }
  };

  stage(0, 0);
  __syncthreads();
  int cur = 0;
  for (int kt = 0; kt < K; kt += 64) {
    if (kt + 64 < K) stage(cur ^ 1, kt + 64);
    compute(cur);
    __syncthreads();
    cur ^= 1;
  }

  // cross-half reduce via LDS (aliases AsBs; all LDS reads drained by last barrier)
  float* red = (float*)&AsBs[0][0][0][0][0];  // 64*65 f32 = 16.6 KB of 64 KB
  int rbase = (lane >> 4) * 4;
  if (half == 1) {
    #pragma unroll
    for (int fm = 0; fm < 2; ++fm)
      #pragma unroll
      for (int fn = 0; fn < 2; ++fn)
        #pragma unroll
        for (int j = 0; j < 4; ++j) {
          int rloc = wr * 32 + fm * 16 + rbase + j;
          int cloc = wc * 32 + fn * 16 + lrow;
          red[rloc * 65 + cloc] = acc[fm][fn][j];
        }
  }
  __syncthreads();
  if (half == 0) {
    #pragma unroll
    for (int fm = 0; fm < 2; ++fm)
      #pragma unroll
      for (int fn = 0; fn < 2; ++fn)
        #pragma unroll
        for (int j = 0; j < 4; ++j) {
          int rloc = wr * 32 + fm * 16 + rbase + j;
          int cloc = wc * 32 + fn * 16 + lrow;
          float sum = acc[fm][fn][j] + red[rloc * 65 + cloc];
          int row = m0 + rloc, col = n0 + cloc;
          if constexpr (EPI == EPI_PART) {
            ((float*)outv)[(size_t)row * Nc + col] = sum;
          } else {  // EPI_RES
            ((float*)outv)[(size_t)row * Nc + col] =
                resid[(size_t)row * Nc + col] + sum + bias[col];
          }
        }
  }
}

// ---------------- fused K-split combine + LayerNorm (x1 f32 + xn bf16) ----------
__global__ __launch_bounds__(128) void comb2ln_k(const float* __restrict__ p,
                                                 const float* __restrict__ resid,
                                                 const float* __restrict__ bias,
                                                 const float* __restrict__ g,
                                                 const float* __restrict__ bl,
                                                 float* __restrict__ x1out,
                                                 ushort* __restrict__ xnout) {
  int row = blockIdx.x, t = threadIdx.x;
  int base = row * H_ + t * 4;
  f32x4 a = *(const f32x4*)&p[base];
  f32x4 r = *(const f32x4*)&resid[base];
  f32x4 bi = *(const f32x4*)&bias[t * 4];
  f32x4 v = r + a + bi;
  *(f32x4*)&x1out[base] = v;
  float s = v[0] + v[1] + v[2] + v[3];
  float sq = v[0] * v[0] + v[1] * v[1] + v[2] * v[2] + v[3] * v[3];
  #pragma unroll
  for (int m = 1; m < 64; m <<= 1) {
    s += __shfl_xor(s, m, 64);
    sq += __shfl_xor(sq, m, 64);
  }
  __shared__ float red[2][2];
  int wid = t >> 6;
  if ((t & 63) == 0) { red[wid][0] = s; red[wid][1] = sq; }
  __syncthreads();
  s = red[0][0] + red[1][0];
  sq = red[0][1] + red[1][1];
  float mu = s * (1.0f / H_);
  float var = sq * (1.0f / H_) - mu * mu;
  float rs = rsqrtf(var + 1e-5f);
  float4 gg = *(const float4*)(g + t * 4);
  float4 bb = *(const float4*)(bl + t * 4);
  ushort4 o;
  o.x = f2bf((v[0] - mu) * rs * gg.x + bb.x);
  o.y = f2bf((v[1] - mu) * rs * gg.y + bb.y);
  o.z = f2bf((v[2] - mu) * rs * gg.z + bb.z);
  o.w = f2bf((v[3] - mu) * rs * gg.w + bb.w);
  *(ushort4*)(xnout + (size_t)row * H_ + t * 4) = o;
}

// ---------------- MFMA flash attention, j-split, dbuf LDS, reg-resident bias ----
constexpr int QT = 64, KT = 64, NJH = 2, NTH = N_ / (KT * NJH);  // 8 tiles/block
constexpr int JH = N_ / NJH;  // 512

__global__ __launch_bounds__(256) void attn_k(
    const ushort* __restrict__ q, const ushort* __restrict__ k,
    const ushort* __restrict__ v, const float* __restrict__ dist,
    const int* __restrict__ mask, const float2* __restrict__ tab2g,
    float* __restrict__ Op, float2* __restrict__ ml) {
  int qt = blockIdx.x, h = blockIdx.y, z = blockIdx.z;
  int b = z >> 1, jh = z & 1;
  int i0 = qt * QT;
  int jbase = jh * JH;
  __shared__ ushort Ks[2][KT * 64];  // [j][d], chunk ^= (j&7)
  __shared__ ushort Vt[2][64 * KT];  // [d][j], chunk ^= (d&7)
  __shared__ ushort Ps[4][16 * 64];  // per-warp P [q][j], chunk ^= (q&7)
  __shared__ float2 tl2[TAB_ + 1];
  __shared__ float mfl[JH];
  int t = threadIdx.x;
  int lane = t & 63, w = t >> 6;
  int l = lane & 15, g = lane >> 4;

  for (int i = t; i <= TAB_; i += 256) tl2[i] = tab2g[h * (TAB_ + 1) + i];
  for (int i = t; i < JH; i += 256) mfl[i] = (mask[b * N_ + jbase + i] == 0) ? -1e9f : 0.0f;

  const size_t ho = ((size_t)(b * NH_ + h)) * N_ * HD_;
  const ushort* qb = q + ho;
  const ushort* kb = k + ho;
  const ushort* vb = v + ho;  // V^T layout: [d][N_]

  int qloc = w * 16 + 4 * g;
  int qrow = i0 + w * 16 + l;
  short8 qf[2];
  qf[0] = *(const short8*)&qb[(size_t)qrow * 64 + g * 8];
  qf[1] = *(const short8*)&qb[(size_t)qrow * 64 + 32 + g * 8];

  int c2 = t & 7, jr = t >> 3;  // K/V staging: chunk 0..7, row 0..31 (+32)

  auto stK = [&](int buf, short8 val, int j2) {
    *(short8*)&Ks[buf][j2 * 64 + ((c2 ^ (j2 & 7)) << 3)] = val;
  };
  auto stV = [&](int buf, short8 val, int d) {
    *(short8*)&Vt[buf][d * 64 + ((c2 ^ (d & 7)) << 3)] = val;
  };

  // dist in MFMA S-layout: row = i0+qloc+reg, col = jbase + tt*KT + fj*16 + l
  const float* dbase = dist + ((size_t)b * N_ + (i0 + qloc)) * N_ + jbase + l;

  // --- prologue: load + stage tile 0 ---
  short8 k0a, k1a, v0a, v1a;
  float ddc[4][4], ddn[4][4];
  {
    const ushort* kn = kb + (size_t)jbase * 64;
    const ushort* vn = vb + jbase;
    k0a = *(const short8*)&kn[(size_t)jr * 64 + c2 * 8];
    k1a = *(const short8*)&kn[(size_t)(jr + 32) * 64 + c2 * 8];
    v0a = *(const short8*)&vn[(size_t)jr * N_ + c2 * 8];
    v1a = *(const short8*)&vn[(size_t)(jr + 32) * N_ + c2 * 8];
    #pragma unroll
    for (int reg = 0; reg < 4; ++reg)
      #pragma unroll
      for (int fj = 0; fj < 4; ++fj)
        ddc[reg][fj] = dbase[(size_t)reg * N_ + fj * 16];
  }
  __syncthreads();  // tl2 + mfl ready
  stK(0, k0a, jr); stK(0, k1a, jr + 32);
  stV(0, v0a, jr); stV(0, v1a, jr + 32);
  __syncthreads();

  float m_[4] = {-1e30f, -1e30f, -1e30f, -1e30f};
  float l_[4] = {0.f, 0.f, 0.f, 0.f};
  f32x4 acc[4] = {{0,0,0,0},{0,0,0,0},{0,0,0,0},{0,0,0,0}};

  int cur = 0;
  for (int tt = 0; tt < NTH; ++tt) {
    const int j0 = jbase + tt * KT;
    if (tt + 1 < NTH) {
      const ushort* kn = kb + (size_t)(j0 + KT) * 64;
      const ushort* vn = vb + (j0 + KT);
      k0a = *(const short8*)&kn[(size_t)jr * 64 + c2 * 8];
      k1a = *(const short8*)&kn[(size_t)(jr + 32) * 64 + c2 * 8];
      v0a = *(const short8*)&vn[(size_t)jr * N_ + c2 * 8];
      v1a = *(const short8*)&vn[(size_t)(jr + 32) * N_ + c2 * 8];
      #pragma unroll
      for (int reg = 0; reg < 4; ++reg)
        #pragma unroll
        for (int fj = 0; fj < 4; ++fj)
          ddn[reg][fj] = dbase[(size_t)reg * N_ + (tt + 1) * KT + fj * 16];
    }
    // S = Q K^T
    f32x4 sa[4] = {{0,0,0,0},{0,0,0,0},{0,0,0,0},{0,0,0,0}};
    __builtin_amdgcn_s_setprio(1);
    #pragma unroll
    for (int dblk = 0; dblk < 2; ++dblk)
      #pragma unroll
      for (int fj = 0; fj < 4; ++fj) {
        int j2 = fj * 16 + l;
        short8 kf = *(const short8*)&Ks[cur][j2 * 64 + (((dblk * 4 + g) ^ (j2 & 7)) << 3)];
        sa[fj] = __builtin_amdgcn_mfma_f32_16x16x32_bf16(qf[dblk], kf, sa[fj], 0, 0, 0);
      }
    __builtin_amdgcn_s_setprio(0);
    // softmax: bias = table-lerp(dist in regs) + mask
    float al_[4];
    #pragma unroll
    for (int reg = 0; reg < 4; ++reg) {
      float svr[4];
      #pragma unroll
      for (int fj = 0; fj < 4; ++fj) {
        float u = ddc[reg][fj] * ((float)TAB_ / MAXD);
        int it = (int)u;
        it = it < 0 ? 0 : (it > TAB_ - 1 ? TAB_ - 1 : it);
        float f = u - (float)it;
        float2 tv = tl2[it];
        float bias = tv.x + f * (tv.y - tv.x) + mfl[tt * KT + fj * 16 + l];
        svr[fj] = fmaf(sa[fj][reg], 0.125f, bias);
      }
      float rm = fmaxf(fmaxf(svr[0], svr[1]), fmaxf(svr[2], svr[3]));
      rm = fmaxf(rm, __shfl_xor(rm, 1, 64));
      rm = fmaxf(rm, __shfl_xor(rm, 2, 64));
      rm = fmaxf(rm, __shfl_xor(rm, 4, 64));
      rm = fmaxf(rm, __shfl_xor(rm, 8, 64));
      float mn = fmaxf(m_[reg], rm);
      float al = __expf(m_[reg] - mn);
      m_[reg] = mn;
      al_[reg] = al;
      float ps = 0.f;
      int qlq = 4 * g + reg;
      #pragma unroll
      for (int fj = 0; fj < 4; ++fj) {
        float p = __expf(svr[fj] - mn);
        ps += p;
        int c = fj * 2 + (l >> 3);
        Ps[w][qlq * 64 + ((c ^ (qlq & 7)) << 3) + (l & 7)] = f2bf(p);
      }
      ps += __shfl_xor(ps, 1, 64);
      ps += __shfl_xor(ps, 2, 64);
      ps += __shfl_xor(ps, 4, 64);
      ps += __shfl_xor(ps, 8, 64);
      l_[reg] = l_[reg] * al + ps;
    }
    #pragma unroll
    for (int fd = 0; fd < 4; ++fd)
      #pragma unroll
      for (int reg = 0; reg < 4; ++reg) acc[fd][reg] *= al_[reg];
    // O += P V   (P A-frags, V^T B-frags)
    __builtin_amdgcn_s_setprio(1);
    #pragma unroll
    for (int jj = 0; jj < 2; ++jj) {
      short8 pa = *(const short8*)&Ps[w][l * 64 + (((jj * 4 + g) ^ (l & 7)) << 3)];
      #pragma unroll
      for (int fd = 0; fd < 4; ++fd) {
        int d2 = fd * 16 + l;
        short8 vf = *(const short8*)&Vt[cur][d2 * 64 + (((jj * 4 + g) ^ (d2 & 7)) << 3)];
        acc[fd] = __builtin_amdgcn_mfma_f32_16x16x32_bf16(pa, vf, acc[fd], 0, 0, 0);
      }
    }
    __builtin_amdgcn_s_setprio(0);
    // stage tile tt+1 into the other buffer (no race: readers use buf cur)
    if (tt + 1 < NTH) {
      int nb = cur ^ 1;
      stK(nb, k0a, jr); stK(nb, k1a, jr + 32);
      stV(nb, v0a, jr); stV(nb, v1a, jr + 32);
      #pragma unroll
      for (int reg = 0; reg < 4; ++reg)
        #pragma unroll
        for (int fj = 0; fj < 4; ++fj) ddc[reg][fj] = ddn[reg][fj];
    }
    __syncthreads();
    cur ^= 1;
  }
  // epilogue: unnormalized partials + (m,l)
  const size_t pbase = (((size_t)(b * NJH + jh) * NH_ + h) * N_) + i0;
  #pragma unroll
  for (int reg = 0; reg < 4; ++reg) {
    int rowl = w * 16 + 4 * g + reg;
    float* op = Op + (pbase + rowl) * HD_ + l;
    #pragma unroll
    for (int fd = 0; fd < 4; ++fd) op[fd * 16] = acc[fd][reg];
    if (l == 0) ml[pbase + rowl] = make_float2(m_[reg], l_[reg]);
  }
}

// ---------------- combine j-split partials ----------------
__global__ __launch_bounds__(256) void comb_k(const float* __restrict__ Op,
                                              const float2* __restrict__ ml,
                                              ushort* __restrict__ ao) {
  int idx = blockIdx.x * 256 + threadIdx.x;
  int row = idx >> 4;
  int dq = (idx & 15) * 4;
  int b = row >> 13, h = (row >> 10) & 7, n = row & 1023;
  size_t p0 = (((size_t)(b * NJH + 0) * NH_ + h) * N_) + n;
  size_t p1 = (((size_t)(b * NJH + 1) * NH_ + h) * N_) + n;
  float2 v0 = ml[p0], v1 = ml[p1];
  float M = fmaxf(v0.x, v1.x);
  float a0 = __expf(v0.x - M), a1 = __expf(v1.x - M);
  float inv = 1.0f / (v0.y * a0 + v1.y * a1);
  float4 O0 = *(const float4*)&Op[p0 * HD_ + dq];
  float4 O1 = *(const float4*)&Op[p1 * HD_ + dq];
  ushort4 o;
  o.x = f2bf((O0.x * a0 + O1.x * a1) * inv);
  o.y = f2bf((O0.y * a0 + O1.y * a1) * inv);
  o.z = f2bf((O0.z * a0 + O1.z * a1) * inv);
  o.w = f2bf((O0.w * a0 + O1.w * a1) * inv);
  *(ushort4*)&ao[((size_t)(b * N_ + n)) * H_ + h * HD_ + dq] = o;
}

extern "C" void kernel_launch(void* const* d_in, const int* in_sizes, int n_in,
                              void* d_out, int out_size, void* d_ws, size_t ws_size,
                              hipStream_t stream) {
  const float* x = (const float*)d_in[0];
  const float* distances = (const float*)d_in[1];
  const int* mask = (const int*)d_in[2];
  const float* widths = (const float*)d_in[3];
  const float* dp_w = (const float*)d_in[4];
  const float* dp_b = (const float*)d_in[5];
  const float* wq = (const float*)d_in[6];
  const float* bq = (const float*)d_in[7];
  const float* wk = (const float*)d_in[8];
  const float* bk = (const float*)d_in[9];
  const float* wv = (const float*)d_in[10];
  const float* bv = (const float*)d_in[11];
  const float* wo = (const float*)d_in[12];
  const float* bo = (const float*)d_in[13];
  const float* ln1_g = (const float*)d_in[14];
  const float* ln1_b = (const float*)d_in[15];
  const float* ln2_g = (const float*)d_in[16];
  const float* ln2_b = (const float*)d_in[17];
  const float* w1 = (const float*)d_in[18];
  const float* b1 = (const float*)d_in[19];
  const float* w2 = (const float*)d_in[20];
  const float* b2 = (const float*)d_in[21];
  float* out = (float*)d_out;
  float* wsf = (float*)d_ws;

  const size_t M1 = (size_t)1 << 20;
  ushort* qkvb = (ushort*)wsf;                       // 3M bf16 (V transposed)
  float* x1 = wsf + 2 * M1;                          // 1M f32
  ushort* hbuf = (ushort*)(wsf + 3 * M1);            // 4M bf16
  ushort* xn = (ushort*)(wsf + 5 * M1);              // 1M bf16
  ushort* xn2 = (ushort*)(wsf + 5 * M1 + M1 / 2);
  ushort* ao = (ushort*)(wsf + 6 * M1);              // 1M bf16
  ushort* wT4 = (ushort*)(wsf + 6 * M1 + M1 / 2);    // 4x 512x512 bf16
  ushort* w1T = (ushort*)(wsf + 7 * M1);             // [2048][512] bf16
  ushort* w2T = (ushort*)(wsf + 7 * M1 + M1 / 2);    // [512][2048] bf16
  float2* tab2 = (float2*)(wsf + 8 * M1);            // 8200 float2
  float* Op = wsf + 9 * M1;                          // 2M f32 attn partials
  float2* ml = (float2*)(wsf + 11 * M1);             // 32K float2
  float* pAO = wsf + 12 * M1;                        // 1M f32 O-proj partial

  prep_k<<<4129, 256, 0, stream>>>(wq, wk, wv, wo, w1, w2, wT4, w1T, w2T,
                                   widths, dp_w, dp_b, tab2, x, ln1_g, ln1_b, xn);

  mfma_gemm<64, 64, EPI_QKV><<<dim3(8, 32, 3), 256, 0, stream>>>(
      xn, wT4, bq, bk, bv, nullptr, qkvb, 512, 512, 512);

  attn_k<<<dim3(N_ / QT, NH_, B_ * NJH), 256, 0, stream>>>(
      qkvb, qkvb + M1, qkvb + 2 * M1, distances, mask, tab2, Op, ml);
  comb_k<<<1024, 256, 0, stream>>>(Op, ml, ao);

  // attn-O projection: in-block K-split x2, single partial; fused combine+LN2
  mfma_gemm2<EPI_PART><<<dim3(8, 32), 512, 0, stream>>>(
      ao, wT4 + (size_t)3 * 512 * 512, bo, nullptr, pAO, 256, 512, 512);
  comb2ln_k<<<B_ * N_, 128, 0, stream>>>(pAO, x, bo, ln2_g, ln2_b, x1, xn2);

  // FFN1: 128x64 tiles -> 512 blocks (2/CU)
  mfma_gemm<128, 64, EPI_GELU><<<dim3(32, 16, 1), 256, 0, stream>>>(
      xn2, w1T, b1, b1, b1, nullptr, hbuf, 512, 512, 2048);

  // FFN2: in-block K-split x2, fully fused epilogue (resid + bias -> out)
  mfma_gemm2<EPI_RES><<<dim3(8, 32), 512, 0, stream>>>(
      hbuf, w2T, b2, x1, out, 1024, 2048, 512);
}

// Round 20
// 95.048 us; speedup vs baseline: 1.8986x; 1.0172x over previous
//
#include <hip/hip_runtime.h>
#include <hip/hip_bf16.h>
#include <math.h>

#define B_ 2
#define N_ 1024
#define H_ 512
#define NH_ 8
#define HD_ 64
#define G_ 50
#define TAB_ 1024
constexpr float MAXD = 10.0f;

typedef __attribute__((ext_vector_type(8))) short short8;
typedef __attribute__((ext_vector_type(4))) float f32x4;

__device__ inline ushort f2bf(float v) {
  __hip_bfloat16 h = __float2bfloat16(v);
  return *(ushort*)&h;
}
__device__ inline float bf2f(ushort u) {
  unsigned x = ((unsigned)u) << 16;
  return __uint_as_float(x);
}
__device__ inline void gload_lds16(const ushort* g, ushort* l) {
  __builtin_amdgcn_global_load_lds(
      (const __attribute__((address_space(1))) void*)g,
      (__attribute__((address_space(3))) void*)l, 16, 0, 0);
}

// ---------------- fused prep: 3 weight transposes + bias table + LN1 ----------------
__device__ inline void transp_dev(const float* __restrict__ src,
                                  ushort* __restrict__ d, int R, int C,
                                  int bx, int by, int t, float (*tile)[33]) {
  int r0 = by * 32, c0 = bx * 32;
  int rr = t >> 5, cc = t & 31;
  #pragma unroll
  for (int p = 0; p < 4; ++p)
    tile[rr + p * 8][cc] = src[(size_t)(r0 + rr + p * 8) * C + c0 + cc];
  __syncthreads();
  #pragma unroll
  for (int p = 0; p < 4; ++p)
    d[(size_t)(c0 + rr + p * 8) * R + r0 + cc] = f2bf(tile[cc][rr + p * 8]);
}

__global__ __launch_bounds__(256) void prep_k(
    const float* wq, const float* wk, const float* wv, const float* wo,
    const float* w1, const float* w2, ushort* __restrict__ wT4,
    ushort* __restrict__ w1T, ushort* __restrict__ w2T,
    const float* __restrict__ widths, const float* __restrict__ dp_w,
    const float* __restrict__ dp_b, float2* __restrict__ tab2,
    const float* __restrict__ x, const float* __restrict__ ln1g,
    const float* __restrict__ ln1b, ushort* __restrict__ xn) {
  __shared__ float tile[32][33];
  __shared__ float red2[4][2];
  int bid = blockIdx.x, t = threadIdx.x;
  if (bid < 1024) {
    int z = bid >> 8, rem = bid & 255;
    const float* src = (z == 0) ? wq : (z == 1) ? wk : (z == 2) ? wv : wo;
    transp_dev(src, wT4 + (size_t)z * 512 * 512, 512, 512, rem & 15, rem >> 4, t, tile);
  } else if (bid < 2048) {
    int rem = bid - 1024;
    transp_dev(w1, w1T, 512, 2048, rem & 63, rem >> 6, t, tile);
  } else if (bid < 3072) {
    int rem = bid - 2048;
    transp_dev(w2, w2T, 2048, 512, rem & 15, rem >> 4, t, tile);
  } else if (bid < 3105) {
    int i = (bid - 3072) * 256 + t;
    if (i >= NH_ * (TAB_ + 1)) return;
    int h = i / (TAB_ + 1), tt = i % (TAB_ + 1);
    int t1 = tt < TAB_ ? tt + 1 : tt;
    float d0 = (float)tt * (MAXD / TAB_);
    float d1 = (float)t1 * (MAXD / TAB_);
    float v0 = dp_b[h], v1 = dp_b[h];
    for (int g = 0; g < G_; ++g) {
      float c = (float)g * (MAXD / 49.0f);
      float w = widths[g];
      float inv = -1.0f / (2.0f * w * w);
      float wg = dp_w[g * NH_ + h];
      float e0 = d0 - c, e1 = d1 - c;
      v0 += expf(e0 * e0 * inv) * wg;
      v1 += expf(e1 * e1 * inv) * wg;
    }
    tab2[i] = make_float2(v0, v1);
  } else {
    // LN1: 2 rows per block (128 threads each)
    int row = (bid - 3105) * 2 + (t >> 7);
    int tl = t & 127;
    float4 v = *(const float4*)(x + (size_t)row * H_ + tl * 4);
    float s = v.x + v.y + v.z + v.w;
    float sq = v.x * v.x + v.y * v.y + v.z * v.z + v.w * v.w;
    #pragma unroll
    for (int m = 1; m < 64; m <<= 1) {
      s += __shfl_xor(s, m, 64);
      sq += __shfl_xor(sq, m, 64);
    }
    int wid = t >> 6;
    if ((t & 63) == 0) { red2[wid][0] = s; red2[wid][1] = sq; }
    __syncthreads();
    int rw = (t >> 7) * 2;
    s = red2[rw][0] + red2[rw + 1][0];
    sq = red2[rw][1] + red2[rw + 1][1];
    float mu = s * (1.0f / H_);
    float var = sq * (1.0f / H_) - mu * mu;
    float rs = rsqrtf(var + 1e-5f);
    float4 gg = *(const float4*)(ln1g + tl * 4);
    float4 bb = *(const float4*)(ln1b + tl * 4);
    ushort4 o;
    o.x = f2bf((v.x - mu) * rs * gg.x + bb.x);
    o.y = f2bf((v.y - mu) * rs * gg.y + bb.y);
    o.z = f2bf((v.z - mu) * rs * gg.z + bb.z);
    o.w = f2bf((v.w - mu) * rs * gg.w + bb.w);
    *(ushort4*)(xn + (size_t)row * H_ + tl * 4) = o;
  }
}

// ---------------- bf16 MFMA GEMM, gload_lds dbuf, K-chunk 64 (2 subs) ----------
enum { EPI_QKV = 1, EPI_RES = 2, EPI_GELU = 3, EPI_PART = 4 };

template <int BM, int BN, int EPI>
__global__ __launch_bounds__(256) void mfma_gemm(const ushort* __restrict__ A,
                                                 const ushort* __restrict__ Bt,
                                                 const float* __restrict__ b0,
                                                 const float* __restrict__ b1,
                                                 const float* __restrict__ b2,
                                                 const float* __restrict__ resid,
                                                 void* __restrict__ outv,
                                                 int K, int Ks, int Nc) {
  __shared__ ushort As[2][2][BM * 32];  // [buf][sub]
  __shared__ ushort Bs[2][2][BN * 32];
  int t = threadIdx.x;
  int z = blockIdx.z;
  const ushort* Bz = Bt + (size_t)z * Nc * Ks;
  const float* bias = (z == 0) ? b0 : (z == 1) ? b1 : b2;
  int m0 = blockIdx.y * BM, n0 = blockIdx.x * BN;
  int lane = t & 63, w = t >> 6, wr = w >> 1, wc = w & 1;
  int lrow = lane & 15, lkg = lane >> 4;
  constexpr int NFM = BM / 32, NFN = BN / 32;
  constexpr int AL = BM / 64, BL = BN / 64;
  f32x4 acc[NFM][NFN] = {};
  int rl = lane >> 2, kgl = lane & 3;

  auto stage = [&](int buf, int kt) {
    #pragma unroll
    for (int sub = 0; sub < 2; ++sub) {
      #pragma unroll
      for (int p = 0; p < AL; ++p) {
        int r = w * (BM / 4) + p * 16 + rl;
        int kgs = kgl ^ (r & 3);
        gload_lds16(&A[(size_t)(m0 + r) * Ks + kt + sub * 32 + kgs * 8],
                    &As[buf][sub][(w * (BM / 4) + p * 16) * 32]);
      }
      #pragma unroll
      for (int p = 0; p < BL; ++p) {
        int r = w * (BN / 4) + p * 16 + rl;
        int kgs = kgl ^ (r & 3);
        gload_lds16(&Bz[(size_t)(n0 + r) * Ks + kt + sub * 32 + kgs * 8],
                    &Bs[buf][sub][(w * (BN / 4) + p * 16) * 32]);
      }
    }
  };
  auto compute = [&](int buf) {
    #pragma unroll
    for (int sub = 0; sub < 2; ++sub) {
      short8 af[NFM], bfr[NFN];
      #pragma unroll
      for (int fm = 0; fm < NFM; ++fm) {
        int r = wr * (BM / 2) + fm * 16 + lrow;
        af[fm] = *(const short8*)&As[buf][sub][r * 32 + ((lkg ^ (r & 3)) << 3)];
      }
      #pragma unroll
      for (int fn = 0; fn < NFN; ++fn) {
        int r = wc * (BN / 2) + fn * 16 + lrow;
        bfr[fn] = *(const short8*)&Bs[buf][sub][r * 32 + ((lkg ^ (r & 3)) << 3)];
      }
      #pragma unroll
      for (int fm = 0; fm < NFM; ++fm)
        #pragma unroll
        for (int fn = 0; fn < NFN; ++fn)
          acc[fm][fn] = __builtin_amdgcn_mfma_f32_16x16x32_bf16(af[fm], bfr[fn],
                                                                acc[fm][fn], 0, 0, 0);
    }
  };

  stage(0, 0);
  __syncthreads();
  int cur = 0;
  for (int kt = 0; kt < K; kt += 64) {
    if (kt + 64 < K) stage(cur ^ 1, kt + 64);
    compute(cur);
    __syncthreads();
    cur ^= 1;
  }

  int rbase = (lane >> 4) * 4;
  if constexpr (EPI == EPI_QKV) {
    if (z < 2) {
      #pragma unroll
      for (int fm = 0; fm < NFM; ++fm)
        #pragma unroll
        for (int fn = 0; fn < NFN; ++fn)
          #pragma unroll
          for (int j = 0; j < 4; ++j) {
            int row = m0 + wr * (BM / 2) + fm * 16 + rbase + j;
            int col = n0 + wc * (BN / 2) + fn * 16 + lrow;
            float v = acc[fm][fn][j] + bias[col];
            ushort* q = (ushort*)outv + (size_t)z * (1 << 20);
            int bb = row >> 10, n = row & (N_ - 1);
            int h = col >> 6, d = col & 63;
            q[(((size_t)(bb * NH_ + h)) * N_ + n) * HD_ + d] = f2bf(v);
          }
    } else {
      // V: transpose via LDS, write coalesced 32B/thread lines along n
      __shared__ float vtile[64 * 65];
      #pragma unroll
      for (int fm = 0; fm < NFM; ++fm)
        #pragma unroll
        for (int fn = 0; fn < NFN; ++fn)
          #pragma unroll
          for (int j = 0; j < 4; ++j) {
            int rloc = wr * (BM / 2) + fm * 16 + rbase + j;
            int cloc = wc * (BN / 2) + fn * 16 + lrow;
            vtile[rloc * 65 + cloc] = acc[fm][fn][j] + bias[n0 + cloc];
          }
      __syncthreads();
      int d_ = t & 63, nc = t >> 6;
      int h = n0 >> 6;
      int bb = m0 >> 10, nbase = m0 & (N_ - 1);
      ushort* dst = (ushort*)outv + (size_t)2 * (1 << 20) +
                    (((size_t)(bb * NH_ + h)) * HD_ + d_) * N_ + nbase + nc * 16;
      short8 o0, o1;
      #pragma unroll
      for (int i = 0; i < 8; ++i) {
        o0[i] = (short)f2bf(vtile[(nc * 16 + i) * 65 + d_]);
        o1[i] = (short)f2bf(vtile[(nc * 16 + 8 + i) * 65 + d_]);
      }
      *(short8*)&dst[0] = o0;
      *(short8*)&dst[8] = o1;
    }
  } else {
    #pragma unroll
    for (int fm = 0; fm < NFM; ++fm) {
      #pragma unroll
      for (int fn = 0; fn < NFN; ++fn) {
        #pragma unroll
        for (int j = 0; j < 4; ++j) {
          int row = m0 + wr * (BM / 2) + fm * 16 + rbase + j;
          int col = n0 + wc * (BN / 2) + fn * 16 + lrow;
          float v = acc[fm][fn][j] + bias[col];
          if constexpr (EPI == EPI_RES) {
            ((float*)outv)[(size_t)row * Nc + col] =
                resid[(size_t)row * Nc + col] + v;
          } else {  // GELU -> bf16
            ((ushort*)outv)[(size_t)row * Nc + col] =
                f2bf(0.5f * v * (1.0f + erff(v * 0.70710678118654752f)));
          }
        }
      }
    }
  }
}

// ---------------- 512-thread GEMM, in-block K-split x2, K-chunk 64 ----------
template <int EPI>
__global__ __launch_bounds__(512) void mfma_gemm2(const ushort* __restrict__ A,
                                                  const ushort* __restrict__ Bt,
                                                  const float* __restrict__ bias,
                                                  const float* __restrict__ resid,
                                                  void* __restrict__ outv,
                                                  int K, int Ks, int Nc) {
  constexpr int BM = 64, BN = 64;
  __shared__ ushort AsBs[2][2][2][2][BM * 32];  // [A/B][half][buf][sub]
  int t = threadIdx.x;
  int half = t >> 8;
  int lane = t & 63;
  int wl = (t >> 6) & 3;  // wave within half
  int wr = wl >> 1, wc = wl & 1;
  int lrow = lane & 15, lkg = lane >> 4;
  int k0 = half * K;
  int m0 = blockIdx.y * BM, n0 = blockIdx.x * BN;
  f32x4 acc[2][2] = {};
  int rl = lane >> 2, kgl = lane & 3;

  auto stage = [&](int buf, int kt) {
    int r = wl * 16 + rl;
    int kgs = kgl ^ (r & 3);
    #pragma unroll
    for (int sub = 0; sub < 2; ++sub) {
      int kk = k0 + kt + sub * 32;
      gload_lds16(&A[(size_t)(m0 + r) * Ks + kk + kgs * 8],
                  &AsBs[0][half][buf][sub][(wl * 16) * 32]);
      gload_lds16(&Bt[(size_t)(n0 + r) * Ks + kk + kgs * 8],
                  &AsBs[1][half][buf][sub][(wl * 16) * 32]);
    }
  };
  auto compute = [&](int buf) {
    #pragma unroll
    for (int sub = 0; sub < 2; ++sub) {
      short8 af[2], bfr[2];
      #pragma unroll
      for (int fm = 0; fm < 2; ++fm) {
        int r = wr * 32 + fm * 16 + lrow;
        af[fm] = *(const short8*)&AsBs[0][half][buf][sub][r * 32 + ((lkg ^ (r & 3)) << 3)];
      }
      #pragma unroll
      for (int fn = 0; fn < 2; ++fn) {
        int r = wc * 32 + fn * 16 + lrow;
        bfr[fn] = *(const short8*)&AsBs[1][half][buf][sub][r * 32 + ((lkg ^ (r & 3)) << 3)];
      }
      #pragma unroll
      for (int fm = 0; fm < 2; ++fm)
        #pragma unroll
        for (int fn = 0; fn < 2; ++fn)
          acc[fm][fn] = __builtin_amdgcn_mfma_f32_16x16x32_bf16(af[fm], bfr[fn],
                                                                acc[fm][fn], 0, 0, 0);
    }
  };

  stage(0, 0);
  __syncthreads();
  int cur = 0;
  for (int kt = 0; kt < K; kt += 64) {
    if (kt + 64 < K) stage(cur ^ 1, kt + 64);
    compute(cur);
    __syncthreads();
    cur ^= 1;
  }

  // cross-half reduce via LDS (aliases AsBs; all LDS reads drained by last barrier)
  float* red = (float*)&AsBs[0][0][0][0][0];  // 64*65 f32 = 16.6 KB of 64 KB
  int rbase = (lane >> 4) * 4;
  if (half == 1) {
    #pragma unroll
    for (int fm = 0; fm < 2; ++fm)
      #pragma unroll
      for (int fn = 0; fn < 2; ++fn)
        #pragma unroll
        for (int j = 0; j < 4; ++j) {
          int rloc = wr * 32 + fm * 16 + rbase + j;
          int cloc = wc * 32 + fn * 16 + lrow;
          red[rloc * 65 + cloc] = acc[fm][fn][j];
        }
  }
  __syncthreads();
  if (half == 0) {
    #pragma unroll
    for (int fm = 0; fm < 2; ++fm)
      #pragma unroll
      for (int fn = 0; fn < 2; ++fn)
        #pragma unroll
        for (int j = 0; j < 4; ++j) {
          int rloc = wr * 32 + fm * 16 + rbase + j;
          int cloc = wc * 32 + fn * 16 + lrow;
          float sum = acc[fm][fn][j] + red[rloc * 65 + cloc];
          int row = m0 + rloc, col = n0 + cloc;
          if constexpr (EPI == EPI_PART) {
            ((float*)outv)[(size_t)row * Nc + col] = sum;
          } else {  // EPI_RES
            ((float*)outv)[(size_t)row * Nc + col] =
                resid[(size_t)row * Nc + col] + sum + bias[col];
          }
        }
  }
}

// ---------------- fused K-split combine + LayerNorm (x1 f32 + xn bf16) ----------
__global__ __launch_bounds__(128) void comb2ln_k(const float* __restrict__ p,
                                                 const float* __restrict__ resid,
                                                 const float* __restrict__ bias,
                                                 const float* __restrict__ g,
                                                 const float* __restrict__ bl,
                                                 float* __restrict__ x1out,
                                                 ushort* __restrict__ xnout) {
  int row = blockIdx.x, t = threadIdx.x;
  int base = row * H_ + t * 4;
  f32x4 a = *(const f32x4*)&p[base];
  f32x4 r = *(const f32x4*)&resid[base];
  f32x4 bi = *(const f32x4*)&bias[t * 4];
  f32x4 v = r + a + bi;
  *(f32x4*)&x1out[base] = v;
  float s = v[0] + v[1] + v[2] + v[3];
  float sq = v[0] * v[0] + v[1] * v[1] + v[2] * v[2] + v[3] * v[3];
  #pragma unroll
  for (int m = 1; m < 64; m <<= 1) {
    s += __shfl_xor(s, m, 64);
    sq += __shfl_xor(sq, m, 64);
  }
  __shared__ float red[2][2];
  int wid = t >> 6;
  if ((t & 63) == 0) { red[wid][0] = s; red[wid][1] = sq; }
  __syncthreads();
  s = red[0][0] + red[1][0];
  sq = red[0][1] + red[1][1];
  float mu = s * (1.0f / H_);
  float var = sq * (1.0f / H_) - mu * mu;
  float rs = rsqrtf(var + 1e-5f);
  float4 gg = *(const float4*)(g + t * 4);
  float4 bb = *(const float4*)(bl + t * 4);
  ushort4 o;
  o.x = f2bf((v[0] - mu) * rs * gg.x + bb.x);
  o.y = f2bf((v[1] - mu) * rs * gg.y + bb.y);
  o.z = f2bf((v[2] - mu) * rs * gg.z + bb.z);
  o.w = f2bf((v[3] - mu) * rs * gg.w + bb.w);
  *(ushort4*)(xnout + (size_t)row * H_ + t * 4) = o;
}

// ---------------- MFMA flash attention, j-split, dbuf LDS, reg-resident bias ----
constexpr int QT = 64, KT = 64, NJH = 2, NTH = N_ / (KT * NJH);  // 8 tiles/block
constexpr int JH = N_ / NJH;  // 512

__global__ __launch_bounds__(256) void attn_k(
    const ushort* __restrict__ q, const ushort* __restrict__ k,
    const ushort* __restrict__ v, const float* __restrict__ dist,
    const int* __restrict__ mask, const float2* __restrict__ tab2g,
    float* __restrict__ Op, float2* __restrict__ ml) {
  int qt = blockIdx.x, h = blockIdx.y, z = blockIdx.z;
  int b = z >> 1, jh = z & 1;
  int i0 = qt * QT;
  int jbase = jh * JH;
  __shared__ ushort Ks[2][KT * 64];  // [j][d], chunk ^= (j&7)
  __shared__ ushort Vt[2][64 * KT];  // [d][j], chunk ^= (d&7)
  __shared__ ushort Ps[4][16 * 64];  // per-warp P [q][j], chunk ^= (q&7)
  __shared__ float2 tl2[TAB_ + 1];
  __shared__ float mfl[JH];
  int t = threadIdx.x;
  int lane = t & 63, w = t >> 6;
  int l = lane & 15, g = lane >> 4;

  for (int i = t; i <= TAB_; i += 256) tl2[i] = tab2g[h * (TAB_ + 1) + i];
  for (int i = t; i < JH; i += 256) mfl[i] = (mask[b * N_ + jbase + i] == 0) ? -1e9f : 0.0f;

  const size_t ho = ((size_t)(b * NH_ + h)) * N_ * HD_;
  const ushort* qb = q + ho;
  const ushort* kb = k + ho;
  const ushort* vb = v + ho;  // V^T layout: [d][N_]

  int qloc = w * 16 + 4 * g;
  int qrow = i0 + w * 16 + l;
  short8 qf[2];
  qf[0] = *(const short8*)&qb[(size_t)qrow * 64 + g * 8];
  qf[1] = *(const short8*)&qb[(size_t)qrow * 64 + 32 + g * 8];

  int c2 = t & 7, jr = t >> 3;  // K/V staging: chunk 0..7, row 0..31 (+32)

  auto stK = [&](int buf, short8 val, int j2) {
    *(short8*)&Ks[buf][j2 * 64 + ((c2 ^ (j2 & 7)) << 3)] = val;
  };
  auto stV = [&](int buf, short8 val, int d) {
    *(short8*)&Vt[buf][d * 64 + ((c2 ^ (d & 7)) << 3)] = val;
  };

  // dist in MFMA S-layout: row = i0+qloc+reg, col = jbase + tt*KT + fj*16 + l
  const float* dbase = dist + ((size_t)b * N_ + (i0 + qloc)) * N_ + jbase + l;

  // --- prologue: load + stage tile 0 ---
  short8 k0a, k1a, v0a, v1a;
  float ddc[4][4], ddn[4][4];
  {
    const ushort* kn = kb + (size_t)jbase * 64;
    const ushort* vn = vb + jbase;
    k0a = *(const short8*)&kn[(size_t)jr * 64 + c2 * 8];
    k1a = *(const short8*)&kn[(size_t)(jr + 32) * 64 + c2 * 8];
    v0a = *(const short8*)&vn[(size_t)jr * N_ + c2 * 8];
    v1a = *(const short8*)&vn[(size_t)(jr + 32) * N_ + c2 * 8];
    #pragma unroll
    for (int reg = 0; reg < 4; ++reg)
      #pragma unroll
      for (int fj = 0; fj < 4; ++fj)
        ddc[reg][fj] = dbase[(size_t)reg * N_ + fj * 16];
  }
  __syncthreads();  // tl2 + mfl ready
  stK(0, k0a, jr); stK(0, k1a, jr + 32);
  stV(0, v0a, jr); stV(0, v1a, jr + 32);
  __syncthreads();

  float m_[4] = {-1e30f, -1e30f, -1e30f, -1e30f};
  float l_[4] = {0.f, 0.f, 0.f, 0.f};
  f32x4 acc[4] = {{0,0,0,0},{0,0,0,0},{0,0,0,0},{0,0,0,0}};

  int cur = 0;
  for (int tt = 0; tt < NTH; ++tt) {
    const int j0 = jbase + tt * KT;
    if (tt + 1 < NTH) {
      const ushort* kn = kb + (size_t)(j0 + KT) * 64;
      const ushort* vn = vb + (j0 + KT);
      k0a = *(const short8*)&kn[(size_t)jr * 64 + c2 * 8];
      k1a = *(const short8*)&kn[(size_t)(jr + 32) * 64 + c2 * 8];
      v0a = *(const short8*)&vn[(size_t)jr * N_ + c2 * 8];
      v1a = *(const short8*)&vn[(size_t)(jr + 32) * N_ + c2 * 8];
      #pragma unroll
      for (int reg = 0; reg < 4; ++reg)
        #pragma unroll
        for (int fj = 0; fj < 4; ++fj)
          ddn[reg][fj] = dbase[(size_t)reg * N_ + (tt + 1) * KT + fj * 16];
    }
    // S = Q K^T
    f32x4 sa[4] = {{0,0,0,0},{0,0,0,0},{0,0,0,0},{0,0,0,0}};
    __builtin_amdgcn_s_setprio(1);
    #pragma unroll
    for (int dblk = 0; dblk < 2; ++dblk)
      #pragma unroll
      for (int fj = 0; fj < 4; ++fj) {
        int j2 = fj * 16 + l;
        short8 kf = *(const short8*)&Ks[cur][j2 * 64 + (((dblk * 4 + g) ^ (j2 & 7)) << 3)];
        sa[fj] = __builtin_amdgcn_mfma_f32_16x16x32_bf16(qf[dblk], kf, sa[fj], 0, 0, 0);
      }
    __builtin_amdgcn_s_setprio(0);
    // softmax: bias = table-lerp(dist in regs) + mask
    float al_[4];
    #pragma unroll
    for (int reg = 0; reg < 4; ++reg) {
      float svr[4];
      #pragma unroll
      for (int fj = 0; fj < 4; ++fj) {
        float u = ddc[reg][fj] * ((float)TAB_ / MAXD);
        int it = (int)u;
        it = it < 0 ? 0 : (it > TAB_ - 1 ? TAB_ - 1 : it);
        float f = u - (float)it;
        float2 tv = tl2[it];
        float bias = tv.x + f * (tv.y - tv.x) + mfl[tt * KT + fj * 16 + l];
        svr[fj] = fmaf(sa[fj][reg], 0.125f, bias);
      }
      float rm = fmaxf(fmaxf(svr[0], svr[1]), fmaxf(svr[2], svr[3]));
      rm = fmaxf(rm, __shfl_xor(rm, 1, 64));
      rm = fmaxf(rm, __shfl_xor(rm, 2, 64));
      rm = fmaxf(rm, __shfl_xor(rm, 4, 64));
      rm = fmaxf(rm, __shfl_xor(rm, 8, 64));
      float mn = fmaxf(m_[reg], rm);
      float al = __expf(m_[reg] - mn);
      m_[reg] = mn;
      al_[reg] = al;
      float ps = 0.f;
      int qlq = 4 * g + reg;
      #pragma unroll
      for (int fj = 0; fj < 4; ++fj) {
        float p = __expf(svr[fj] - mn);
        ps += p;
        int c = fj * 2 + (l >> 3);
        Ps[w][qlq * 64 + ((c ^ (qlq & 7)) << 3) + (l & 7)] = f2bf(p);
      }
      ps += __shfl_xor(ps, 1, 64);
      ps += __shfl_xor(ps, 2, 64);
      ps += __shfl_xor(ps, 4, 64);
      ps += __shfl_xor(ps, 8, 64);
      l_[reg] = l_[reg] * al + ps;
    }
    #pragma unroll
    for (int fd = 0; fd < 4; ++fd)
      #pragma unroll
      for (int reg = 0; reg < 4; ++reg) acc[fd][reg] *= al_[reg];
    // O += P V   (P A-frags, V^T B-frags)
    __builtin_amdgcn_s_setprio(1);
    #pragma unroll
    for (int jj = 0; jj < 2; ++jj) {
      short8 pa = *(const short8*)&Ps[w][l * 64 + (((jj * 4 + g) ^ (l & 7)) << 3)];
      #pragma unroll
      for (int fd = 0; fd < 4; ++fd) {
        int d2 = fd * 16 + l;
        short8 vf = *(const short8*)&Vt[cur][d2 * 64 + (((jj * 4 + g) ^ (d2 & 7)) << 3)];
        acc[fd] = __builtin_amdgcn_mfma_f32_16x16x32_bf16(pa, vf, acc[fd], 0, 0, 0);
      }
    }
    __builtin_amdgcn_s_setprio(0);
    // stage tile tt+1 into the other buffer (no race: readers use buf cur)
    if (tt + 1 < NTH) {
      int nb = cur ^ 1;
      stK(nb, k0a, jr); stK(nb, k1a, jr + 32);
      stV(nb, v0a, jr); stV(nb, v1a, jr + 32);
      #pragma unroll
      for (int reg = 0; reg < 4; ++reg)
        #pragma unroll
        for (int fj = 0; fj < 4; ++fj) ddc[reg][fj] = ddn[reg][fj];
    }
    __syncthreads();
    cur ^= 1;
  }
  // epilogue: unnormalized partials + (m,l)
  const size_t pbase = (((size_t)(b * NJH + jh) * NH_ + h) * N_) + i0;
  #pragma unroll
  for (int reg = 0; reg < 4; ++reg) {
    int rowl = w * 16 + 4 * g + reg;
    float* op = Op + (pbase + rowl) * HD_ + l;
    #pragma unroll
    for (int fd = 0; fd < 4; ++fd) op[fd * 16] = acc[fd][reg];
    if (l == 0) ml[pbase + rowl] = make_float2(m_[reg], l_[reg]);
  }
}

// ---------------- combine j-split partials ----------------
__global__ __launch_bounds__(256) void comb_k(const float* __restrict__ Op,
                                              const float2* __restrict__ ml,
                                              ushort* __restrict__ ao) {
  int idx = blockIdx.x * 256 + threadIdx.x;
  int row = idx >> 4;
  int dq = (idx & 15) * 4;
  int b = row >> 13, h = (row >> 10) & 7, n = row & 1023;
  size_t p0 = (((size_t)(b * NJH + 0) * NH_ + h) * N_) + n;
  size_t p1 = (((size_t)(b * NJH + 1) * NH_ + h) * N_) + n;
  float2 v0 = ml[p0], v1 = ml[p1];
  float M = fmaxf(v0.x, v1.x);
  float a0 = __expf(v0.x - M), a1 = __expf(v1.x - M);
  float inv = 1.0f / (v0.y * a0 + v1.y * a1);
  float4 O0 = *(const float4*)&Op[p0 * HD_ + dq];
  float4 O1 = *(const float4*)&Op[p1 * HD_ + dq];
  ushort4 o;
  o.x = f2bf((O0.x * a0 + O1.x * a1) * inv);
  o.y = f2bf((O0.y * a0 + O1.y * a1) * inv);
  o.z = f2bf((O0.z * a0 + O1.z * a1) * inv);
  o.w = f2bf((O0.w * a0 + O1.w * a1) * inv);
  *(ushort4*)&ao[((size_t)(b * N_ + n)) * H_ + h * HD_ + dq] = o;
}

extern "C" void kernel_launch(void* const* d_in, const int* in_sizes, int n_in,
                              void* d_out, int out_size, void* d_ws, size_t ws_size,
                              hipStream_t stream) {
  const float* x = (const float*)d_in[0];
  const float* distances = (const float*)d_in[1];
  const int* mask = (const int*)d_in[2];
  const float* widths = (const float*)d_in[3];
  const float* dp_w = (const float*)d_in[4];
  const float* dp_b = (const float*)d_in[5];
  const float* wq = (const float*)d_in[6];
  const float* bq = (const float*)d_in[7];
  const float* wk = (const float*)d_in[8];
  const float* bk = (const float*)d_in[9];
  const float* wv = (const float*)d_in[10];
  const float* bv = (const float*)d_in[11];
  const float* wo = (const float*)d_in[12];
  const float* bo = (const float*)d_in[13];
  const float* ln1_g = (const float*)d_in[14];
  const float* ln1_b = (const float*)d_in[15];
  const float* ln2_g = (const float*)d_in[16];
  const float* ln2_b = (const float*)d_in[17];
  const float* w1 = (const float*)d_in[18];
  const float* b1 = (const float*)d_in[19];
  const float* w2 = (const float*)d_in[20];
  const float* b2 = (const float*)d_in[21];
  float* out = (float*)d_out;
  float* wsf = (float*)d_ws;

  const size_t M1 = (size_t)1 << 20;
  ushort* qkvb = (ushort*)wsf;                       // 3M bf16 (V transposed)
  float* x1 = wsf + 2 * M1;                          // 1M f32
  ushort* hbuf = (ushort*)(wsf + 3 * M1);            // 4M bf16
  ushort* xn = (ushort*)(wsf + 5 * M1);              // 1M bf16
  ushort* xn2 = (ushort*)(wsf + 5 * M1 + M1 / 2);
  ushort* ao = (ushort*)(wsf + 6 * M1);              // 1M bf16
  ushort* wT4 = (ushort*)(wsf + 6 * M1 + M1 / 2);    // 4x 512x512 bf16
  ushort* w1T = (ushort*)(wsf + 7 * M1);             // [2048][512] bf16
  ushort* w2T = (ushort*)(wsf + 7 * M1 + M1 / 2);    // [512][2048] bf16
  float2* tab2 = (float2*)(wsf + 8 * M1);            // 8200 float2
  float* Op = wsf + 9 * M1;                          // 2M f32 attn partials
  float2* ml = (float2*)(wsf + 11 * M1);             // 32K float2
  float* pAO = wsf + 12 * M1;                        // 1M f32 O-proj partial

  prep_k<<<4129, 256, 0, stream>>>(wq, wk, wv, wo, w1, w2, wT4, w1T, w2T,
                                   widths, dp_w, dp_b, tab2, x, ln1_g, ln1_b, xn);

  mfma_gemm<64, 64, EPI_QKV><<<dim3(8, 32, 3), 256, 0, stream>>>(
      xn, wT4, bq, bk, bv, nullptr, qkvb, 512, 512, 512);

  attn_k<<<dim3(N_ / QT, NH_, B_ * NJH), 256, 0, stream>>>(
      qkvb, qkvb + M1, qkvb + 2 * M1, distances, mask, tab2, Op, ml);
  comb_k<<<1024, 256, 0, stream>>>(Op, ml, ao);

  // attn-O projection: in-block K-split x2, single partial; fused combine+LN2
  mfma_gemm2<EPI_PART><<<dim3(8, 32), 512, 0, stream>>>(
      ao, wT4 + (size_t)3 * 512 * 512, bo, nullptr, pAO, 256, 512, 512);
  comb2ln_k<<<B_ * N_, 128, 0, stream>>>(pAO, x, bo, ln2_g, ln2_b, x1, xn2);

  // FFN1: 128x64 tiles -> 512 blocks (2/CU)
  mfma_gemm<128, 64, EPI_GELU><<<dim3(32, 16, 1), 256, 0, stream>>>(
      xn2, w1T, b1, b1, b1, nullptr, hbuf, 512, 512, 2048);

  // FFN2: in-block K-split x2, fully fused epilogue (resid + bias -> out)
  mfma_gemm2<EPI_RES><<<dim3(8, 32), 512, 0, stream>>>(
      hbuf, w2T, b2, x1, out, 1024, 2048, 512);
}

// Round 21
// 94.728 us; speedup vs baseline: 1.9051x; 1.0034x over previous
//
#include <hip/hip_runtime.h>
#include <hip/hip_bf16.h>
#include <math.h>

#define B_ 2
#define N_ 1024
#define H_ 512
#define NH_ 8
#define HD_ 64
#define G_ 50
#define TAB_ 1024
constexpr float MAXD = 10.0f;

typedef __attribute__((ext_vector_type(8))) short short8;
typedef __attribute__((ext_vector_type(4))) float f32x4;

__device__ inline ushort f2bf(float v) {
  __hip_bfloat16 h = __float2bfloat16(v);
  return *(ushort*)&h;
}
__device__ inline float bf2f(ushort u) {
  unsigned x = ((unsigned)u) << 16;
  return __uint_as_float(x);
}
__device__ inline void gload_lds16(const ushort* g, ushort* l) {
  __builtin_amdgcn_global_load_lds(
      (const __attribute__((address_space(1))) void*)g,
      (__attribute__((address_space(3))) void*)l, 16, 0, 0);
}

// ---------------- fused prep: 3 weight transposes + bias table + LN1 ----------------
__device__ inline void transp_dev(const float* __restrict__ src,
                                  ushort* __restrict__ d, int R, int C,
                                  int bx, int by, int t, float (*tile)[33]) {
  int r0 = by * 32, c0 = bx * 32;
  int rr = t >> 5, cc = t & 31;
  #pragma unroll
  for (int p = 0; p < 4; ++p)
    tile[rr + p * 8][cc] = src[(size_t)(r0 + rr + p * 8) * C + c0 + cc];
  __syncthreads();
  #pragma unroll
  for (int p = 0; p < 4; ++p)
    d[(size_t)(c0 + rr + p * 8) * R + r0 + cc] = f2bf(tile[cc][rr + p * 8]);
}

__global__ __launch_bounds__(256) void prep_k(
    const float* wq, const float* wk, const float* wv, const float* wo,
    const float* w1, const float* w2, ushort* __restrict__ wT4,
    ushort* __restrict__ w1T, ushort* __restrict__ w2T,
    const float* __restrict__ widths, const float* __restrict__ dp_w,
    const float* __restrict__ dp_b, float2* __restrict__ tab2,
    const float* __restrict__ x, const float* __restrict__ ln1g,
    const float* __restrict__ ln1b, ushort* __restrict__ xn) {
  __shared__ float tile[32][33];
  __shared__ float red2[4][2];
  int bid = blockIdx.x, t = threadIdx.x;
  if (bid < 1024) {
    int z = bid >> 8, rem = bid & 255;
    const float* src = (z == 0) ? wq : (z == 1) ? wk : (z == 2) ? wv : wo;
    transp_dev(src, wT4 + (size_t)z * 512 * 512, 512, 512, rem & 15, rem >> 4, t, tile);
  } else if (bid < 2048) {
    int rem = bid - 1024;
    transp_dev(w1, w1T, 512, 2048, rem & 63, rem >> 6, t, tile);
  } else if (bid < 3072) {
    int rem = bid - 2048;
    transp_dev(w2, w2T, 2048, 512, rem & 15, rem >> 4, t, tile);
  } else if (bid < 3105) {
    int i = (bid - 3072) * 256 + t;
    if (i >= NH_ * (TAB_ + 1)) return;
    int h = i / (TAB_ + 1), tt = i % (TAB_ + 1);
    int t1 = tt < TAB_ ? tt + 1 : tt;
    float d0 = (float)tt * (MAXD / TAB_);
    float d1 = (float)t1 * (MAXD / TAB_);
    float v0 = dp_b[h], v1 = dp_b[h];
    for (int g = 0; g < G_; ++g) {
      float c = (float)g * (MAXD / 49.0f);
      float w = widths[g];
      float inv = -1.0f / (2.0f * w * w);
      float wg = dp_w[g * NH_ + h];
      float e0 = d0 - c, e1 = d1 - c;
      v0 += expf(e0 * e0 * inv) * wg;
      v1 += expf(e1 * e1 * inv) * wg;
    }
    tab2[i] = make_float2(v0, v1);
  } else {
    // LN1: 2 rows per block (128 threads each)
    int row = (bid - 3105) * 2 + (t >> 7);
    int tl = t & 127;
    float4 v = *(const float4*)(x + (size_t)row * H_ + tl * 4);
    float s = v.x + v.y + v.z + v.w;
    float sq = v.x * v.x + v.y * v.y + v.z * v.z + v.w * v.w;
    #pragma unroll
    for (int m = 1; m < 64; m <<= 1) {
      s += __shfl_xor(s, m, 64);
      sq += __shfl_xor(sq, m, 64);
    }
    int wid = t >> 6;
    if ((t & 63) == 0) { red2[wid][0] = s; red2[wid][1] = sq; }
    __syncthreads();
    int rw = (t >> 7) * 2;
    s = red2[rw][0] + red2[rw + 1][0];
    sq = red2[rw][1] + red2[rw + 1][1];
    float mu = s * (1.0f / H_);
    float var = sq * (1.0f / H_) - mu * mu;
    float rs = rsqrtf(var + 1e-5f);
    float4 gg = *(const float4*)(ln1g + tl * 4);
    float4 bb = *(const float4*)(ln1b + tl * 4);
    ushort4 o;
    o.x = f2bf((v.x - mu) * rs * gg.x + bb.x);
    o.y = f2bf((v.y - mu) * rs * gg.y + bb.y);
    o.z = f2bf((v.z - mu) * rs * gg.z + bb.z);
    o.w = f2bf((v.w - mu) * rs * gg.w + bb.w);
    *(ushort4*)(xn + (size_t)row * H_ + tl * 4) = o;
  }
}

// ---------------- bf16 MFMA GEMM, gload_lds dbuf, K-chunk 64 (2 subs) ----------
enum { EPI_QKV = 1, EPI_RES = 2, EPI_GELU = 3, EPI_PART = 4 };

template <int BM, int BN, int EPI>
__global__ __launch_bounds__(256) void mfma_gemm(const ushort* __restrict__ A,
                                                 const ushort* __restrict__ Bt,
                                                 const float* __restrict__ b0,
                                                 const float* __restrict__ b1,
                                                 const float* __restrict__ b2,
                                                 const float* __restrict__ resid,
                                                 void* __restrict__ outv,
                                                 int K, int Ks, int Nc) {
  __shared__ ushort As[2][2][BM * 32];  // [buf][sub]
  __shared__ ushort Bs[2][2][BN * 32];
  int t = threadIdx.x;
  int z = blockIdx.z;
  const ushort* Bz = Bt + (size_t)z * Nc * Ks;
  const float* bias = (z == 0) ? b0 : (z == 1) ? b1 : b2;
  int m0 = blockIdx.y * BM, n0 = blockIdx.x * BN;
  int lane = t & 63, w = t >> 6, wr = w >> 1, wc = w & 1;
  int lrow = lane & 15, lkg = lane >> 4;
  constexpr int NFM = BM / 32, NFN = BN / 32;
  constexpr int AL = BM / 64, BL = BN / 64;
  f32x4 acc[NFM][NFN] = {};
  int rl = lane >> 2, kgl = lane & 3;

  auto stage = [&](int buf, int kt) {
    #pragma unroll
    for (int sub = 0; sub < 2; ++sub) {
      #pragma unroll
      for (int p = 0; p < AL; ++p) {
        int r = w * (BM / 4) + p * 16 + rl;
        int kgs = kgl ^ (r & 3);
        gload_lds16(&A[(size_t)(m0 + r) * Ks + kt + sub * 32 + kgs * 8],
                    &As[buf][sub][(w * (BM / 4) + p * 16) * 32]);
      }
      #pragma unroll
      for (int p = 0; p < BL; ++p) {
        int r = w * (BN / 4) + p * 16 + rl;
        int kgs = kgl ^ (r & 3);
        gload_lds16(&Bz[(size_t)(n0 + r) * Ks + kt + sub * 32 + kgs * 8],
                    &Bs[buf][sub][(w * (BN / 4) + p * 16) * 32]);
      }
    }
  };
  auto compute = [&](int buf) {
    #pragma unroll
    for (int sub = 0; sub < 2; ++sub) {
      short8 af[NFM], bfr[NFN];
      #pragma unroll
      for (int fm = 0; fm < NFM; ++fm) {
        int r = wr * (BM / 2) + fm * 16 + lrow;
        af[fm] = *(const short8*)&As[buf][sub][r * 32 + ((lkg ^ (r & 3)) << 3)];
      }
      #pragma unroll
      for (int fn = 0; fn < NFN; ++fn) {
        int r = wc * (BN / 2) + fn * 16 + lrow;
        bfr[fn] = *(const short8*)&Bs[buf][sub][r * 32 + ((lkg ^ (r & 3)) << 3)];
      }
      #pragma unroll
      for (int fm = 0; fm < NFM; ++fm)
        #pragma unroll
        for (int fn = 0; fn < NFN; ++fn)
          acc[fm][fn] = __builtin_amdgcn_mfma_f32_16x16x32_bf16(af[fm], bfr[fn],
                                                                acc[fm][fn], 0, 0, 0);
    }
  };

  stage(0, 0);
  __syncthreads();
  int cur = 0;
  for (int kt = 0; kt < K; kt += 64) {
    if (kt + 64 < K) stage(cur ^ 1, kt + 64);
    compute(cur);
    __syncthreads();
    cur ^= 1;
  }

  int rbase = (lane >> 4) * 4;
  if constexpr (EPI == EPI_QKV) {
    if (z < 2) {
      #pragma unroll
      for (int fm = 0; fm < NFM; ++fm)
        #pragma unroll
        for (int fn = 0; fn < NFN; ++fn)
          #pragma unroll
          for (int j = 0; j < 4; ++j) {
            int row = m0 + wr * (BM / 2) + fm * 16 + rbase + j;
            int col = n0 + wc * (BN / 2) + fn * 16 + lrow;
            float v = acc[fm][fn][j] + bias[col];
            ushort* q = (ushort*)outv + (size_t)z * (1 << 20);
            int bb = row >> 10, n = row & (N_ - 1);
            int h = col >> 6, d = col & 63;
            q[(((size_t)(bb * NH_ + h)) * N_ + n) * HD_ + d] = f2bf(v);
          }
    } else {
      // V: transpose via LDS, write coalesced 32B/thread lines along n
      __shared__ float vtile[64 * 65];
      #pragma unroll
      for (int fm = 0; fm < NFM; ++fm)
        #pragma unroll
        for (int fn = 0; fn < NFN; ++fn)
          #pragma unroll
          for (int j = 0; j < 4; ++j) {
            int rloc = wr * (BM / 2) + fm * 16 + rbase + j;
            int cloc = wc * (BN / 2) + fn * 16 + lrow;
            vtile[rloc * 65 + cloc] = acc[fm][fn][j] + bias[n0 + cloc];
          }
      __syncthreads();
      int d_ = t & 63, nc = t >> 6;
      int h = n0 >> 6;
      int bb = m0 >> 10, nbase = m0 & (N_ - 1);
      ushort* dst = (ushort*)outv + (size_t)2 * (1 << 20) +
                    (((size_t)(bb * NH_ + h)) * HD_ + d_) * N_ + nbase + nc * 16;
      short8 o0, o1;
      #pragma unroll
      for (int i = 0; i < 8; ++i) {
        o0[i] = (short)f2bf(vtile[(nc * 16 + i) * 65 + d_]);
        o1[i] = (short)f2bf(vtile[(nc * 16 + 8 + i) * 65 + d_]);
      }
      *(short8*)&dst[0] = o0;
      *(short8*)&dst[8] = o1;
    }
  } else {
    #pragma unroll
    for (int fm = 0; fm < NFM; ++fm) {
      #pragma unroll
      for (int fn = 0; fn < NFN; ++fn) {
        #pragma unroll
        for (int j = 0; j < 4; ++j) {
          int row = m0 + wr * (BM / 2) + fm * 16 + rbase + j;
          int col = n0 + wc * (BN / 2) + fn * 16 + lrow;
          float v = acc[fm][fn][j] + bias[col];
          if constexpr (EPI == EPI_RES) {
            ((float*)outv)[(size_t)row * Nc + col] =
                resid[(size_t)row * Nc + col] + v;
          } else {  // GELU -> bf16
            ((ushort*)outv)[(size_t)row * Nc + col] =
                f2bf(0.5f * v * (1.0f + erff(v * 0.70710678118654752f)));
          }
        }
      }
    }
  }
}

// ---------------- 512-thread GEMM, in-block K-split x2, K-chunk 64 ----------
template <int EPI>
__global__ __launch_bounds__(512) void mfma_gemm2(const ushort* __restrict__ A,
                                                  const ushort* __restrict__ Bt,
                                                  const float* __restrict__ bias,
                                                  const float* __restrict__ resid,
                                                  void* __restrict__ outv,
                                                  int K, int Ks, int Nc) {
  constexpr int BM = 64, BN = 64;
  __shared__ ushort AsBs[2][2][2][2][BM * 32];  // [A/B][half][buf][sub]
  int t = threadIdx.x;
  int half = t >> 8;
  int lane = t & 63;
  int wl = (t >> 6) & 3;  // wave within half
  int wr = wl >> 1, wc = wl & 1;
  int lrow = lane & 15, lkg = lane >> 4;
  int k0 = half * K;
  int m0 = blockIdx.y * BM, n0 = blockIdx.x * BN;
  f32x4 acc[2][2] = {};
  int rl = lane >> 2, kgl = lane & 3;

  auto stage = [&](int buf, int kt) {
    int r = wl * 16 + rl;
    int kgs = kgl ^ (r & 3);
    #pragma unroll
    for (int sub = 0; sub < 2; ++sub) {
      int kk = k0 + kt + sub * 32;
      gload_lds16(&A[(size_t)(m0 + r) * Ks + kk + kgs * 8],
                  &AsBs[0][half][buf][sub][(wl * 16) * 32]);
      gload_lds16(&Bt[(size_t)(n0 + r) * Ks + kk + kgs * 8],
                  &AsBs[1][half][buf][sub][(wl * 16) * 32]);
    }
  };
  auto compute = [&](int buf) {
    #pragma unroll
    for (int sub = 0; sub < 2; ++sub) {
      short8 af[2], bfr[2];
      #pragma unroll
      for (int fm = 0; fm < 2; ++fm) {
        int r = wr * 32 + fm * 16 + lrow;
        af[fm] = *(const short8*)&AsBs[0][half][buf][sub][r * 32 + ((lkg ^ (r & 3)) << 3)];
      }
      #pragma unroll
      for (int fn = 0; fn < 2; ++fn) {
        int r = wc * 32 + fn * 16 + lrow;
        bfr[fn] = *(const short8*)&AsBs[1][half][buf][sub][r * 32 + ((lkg ^ (r & 3)) << 3)];
      }
      #pragma unroll
      for (int fm = 0; fm < 2; ++fm)
        #pragma unroll
        for (int fn = 0; fn < 2; ++fn)
          acc[fm][fn] = __builtin_amdgcn_mfma_f32_16x16x32_bf16(af[fm], bfr[fn],
                                                                acc[fm][fn], 0, 0, 0);
    }
  };

  stage(0, 0);
  __syncthreads();
  int cur = 0;
  for (int kt = 0; kt < K; kt += 64) {
    if (kt + 64 < K) stage(cur ^ 1, kt + 64);
    compute(cur);
    __syncthreads();
    cur ^= 1;
  }

  // cross-half reduce via LDS (aliases AsBs; all LDS reads drained by last barrier)
  float* red = (float*)&AsBs[0][0][0][0][0];  // 64*65 f32 = 16.6 KB of 64 KB
  int rbase = (lane >> 4) * 4;
  if (half == 1) {
    #pragma unroll
    for (int fm = 0; fm < 2; ++fm)
      #pragma unroll
      for (int fn = 0; fn < 2; ++fn)
        #pragma unroll
        for (int j = 0; j < 4; ++j) {
          int rloc = wr * 32 + fm * 16 + rbase + j;
          int cloc = wc * 32 + fn * 16 + lrow;
          red[rloc * 65 + cloc] = acc[fm][fn][j];
        }
  }
  __syncthreads();
  if (half == 0) {
    #pragma unroll
    for (int fm = 0; fm < 2; ++fm)
      #pragma unroll
      for (int fn = 0; fn < 2; ++fn)
        #pragma unroll
        for (int j = 0; j < 4; ++j) {
          int rloc = wr * 32 + fm * 16 + rbase + j;
          int cloc = wc * 32 + fn * 16 + lrow;
          float sum = acc[fm][fn][j] + red[rloc * 65 + cloc];
          int row = m0 + rloc, col = n0 + cloc;
          if constexpr (EPI == EPI_PART) {
            ((float*)outv)[(size_t)row * Nc + col] = sum;
          } else {  // EPI_RES
            ((float*)outv)[(size_t)row * Nc + col] =
                resid[(size_t)row * Nc + col] + sum + bias[col];
          }
        }
  }
}

// ---------------- LayerNorm only (f32 in -> bf16 out) for LN2 ----------
__global__ __launch_bounds__(128) void ln2_k(const float* __restrict__ x1,
                                             const float* __restrict__ g,
                                             const float* __restrict__ bl,
                                             ushort* __restrict__ xnout) {
  int row = blockIdx.x, t = threadIdx.x;
  int base = row * H_ + t * 4;
  f32x4 v = *(const f32x4*)&x1[base];
  float s = v[0] + v[1] + v[2] + v[3];
  float sq = v[0] * v[0] + v[1] * v[1] + v[2] * v[2] + v[3] * v[3];
  #pragma unroll
  for (int m = 1; m < 64; m <<= 1) {
    s += __shfl_xor(s, m, 64);
    sq += __shfl_xor(sq, m, 64);
  }
  __shared__ float red[2][2];
  int wid = t >> 6;
  if ((t & 63) == 0) { red[wid][0] = s; red[wid][1] = sq; }
  __syncthreads();
  s = red[0][0] + red[1][0];
  sq = red[0][1] + red[1][1];
  float mu = s * (1.0f / H_);
  float var = sq * (1.0f / H_) - mu * mu;
  float rs = rsqrtf(var + 1e-5f);
  float4 gg = *(const float4*)(g + t * 4);
  float4 bb = *(const float4*)(bl + t * 4);
  ushort4 o;
  o.x = f2bf((v[0] - mu) * rs * gg.x + bb.x);
  o.y = f2bf((v[1] - mu) * rs * gg.y + bb.y);
  o.z = f2bf((v[2] - mu) * rs * gg.z + bb.z);
  o.w = f2bf((v[3] - mu) * rs * gg.w + bb.w);
  *(ushort4*)(xnout + (size_t)row * H_ + t * 4) = o;
}

// ---------------- MFMA flash attention, j-split, dbuf LDS, reg-resident bias ----
constexpr int QT = 64, KT = 64, NJH = 2, NTH = N_ / (KT * NJH);  // 8 tiles/block
constexpr int JH = N_ / NJH;  // 512

__global__ __launch_bounds__(256) void attn_k(
    const ushort* __restrict__ q, const ushort* __restrict__ k,
    const ushort* __restrict__ v, const float* __restrict__ dist,
    const int* __restrict__ mask, const float2* __restrict__ tab2g,
    float* __restrict__ Op, float2* __restrict__ ml) {
  int qt = blockIdx.x, h = blockIdx.y, z = blockIdx.z;
  int b = z >> 1, jh = z & 1;
  int i0 = qt * QT;
  int jbase = jh * JH;
  __shared__ ushort Ks[2][KT * 64];  // [j][d], chunk ^= (j&7)
  __shared__ ushort Vt[2][64 * KT];  // [d][j], chunk ^= (d&7)
  __shared__ ushort Ps[4][16 * 64];  // per-warp P [q][j], chunk ^= (q&7)
  __shared__ float2 tl2[TAB_ + 1];
  __shared__ float mfl[JH];
  int t = threadIdx.x;
  int lane = t & 63, w = t >> 6;
  int l = lane & 15, g = lane >> 4;

  for (int i = t; i <= TAB_; i += 256) tl2[i] = tab2g[h * (TAB_ + 1) + i];
  for (int i = t; i < JH; i += 256) mfl[i] = (mask[b * N_ + jbase + i] == 0) ? -1e9f : 0.0f;

  const size_t ho = ((size_t)(b * NH_ + h)) * N_ * HD_;
  const ushort* qb = q + ho;
  const ushort* kb = k + ho;
  const ushort* vb = v + ho;  // V^T layout: [d][N_]

  int qloc = w * 16 + 4 * g;
  int qrow = i0 + w * 16 + l;
  short8 qf[2];
  qf[0] = *(const short8*)&qb[(size_t)qrow * 64 + g * 8];
  qf[1] = *(const short8*)&qb[(size_t)qrow * 64 + 32 + g * 8];

  int c2 = t & 7, jr = t >> 3;  // K/V staging: chunk 0..7, row 0..31 (+32)

  auto stK = [&](int buf, short8 val, int j2) {
    *(short8*)&Ks[buf][j2 * 64 + ((c2 ^ (j2 & 7)) << 3)] = val;
  };
  auto stV = [&](int buf, short8 val, int d) {
    *(short8*)&Vt[buf][d * 64 + ((c2 ^ (d & 7)) << 3)] = val;
  };

  // dist in MFMA S-layout: row = i0+qloc+reg, col = jbase + tt*KT + fj*16 + l
  const float* dbase = dist + ((size_t)b * N_ + (i0 + qloc)) * N_ + jbase + l;

  // --- prologue: load + stage tile 0 ---
  short8 k0a, k1a, v0a, v1a;
  float ddc[4][4], ddn[4][4];
  {
    const ushort* kn = kb + (size_t)jbase * 64;
    const ushort* vn = vb + jbase;
    k0a = *(const short8*)&kn[(size_t)jr * 64 + c2 * 8];
    k1a = *(const short8*)&kn[(size_t)(jr + 32) * 64 + c2 * 8];
    v0a = *(const short8*)&vn[(size_t)jr * N_ + c2 * 8];
    v1a = *(const short8*)&vn[(size_t)(jr + 32) * N_ + c2 * 8];
    #pragma unroll
    for (int reg = 0; reg < 4; ++reg)
      #pragma unroll
      for (int fj = 0; fj < 4; ++fj)
        ddc[reg][fj] = dbase[(size_t)reg * N_ + fj * 16];
  }
  __syncthreads();  // tl2 + mfl ready
  stK(0, k0a, jr); stK(0, k1a, jr + 32);
  stV(0, v0a, jr); stV(0, v1a, jr + 32);
  __syncthreads();

  float m_[4] = {-1e30f, -1e30f, -1e30f, -1e30f};
  float l_[4] = {0.f, 0.f, 0.f, 0.f};
  f32x4 acc[4] = {{0,0,0,0},{0,0,0,0},{0,0,0,0},{0,0,0,0}};

  int cur = 0;
  for (int tt = 0; tt < NTH; ++tt) {
    const int j0 = jbase + tt * KT;
    if (tt + 1 < NTH) {
      const ushort* kn = kb + (size_t)(j0 + KT) * 64;
      const ushort* vn = vb + (j0 + KT);
      k0a = *(const short8*)&kn[(size_t)jr * 64 + c2 * 8];
      k1a = *(const short8*)&kn[(size_t)(jr + 32) * 64 + c2 * 8];
      v0a = *(const short8*)&vn[(size_t)jr * N_ + c2 * 8];
      v1a = *(const short8*)&vn[(size_t)(jr + 32) * N_ + c2 * 8];
      #pragma unroll
      for (int reg = 0; reg < 4; ++reg)
        #pragma unroll
        for (int fj = 0; fj < 4; ++fj)
          ddn[reg][fj] = dbase[(size_t)reg * N_ + (tt + 1) * KT + fj * 16];
    }
    // S = Q K^T
    f32x4 sa[4] = {{0,0,0,0},{0,0,0,0},{0,0,0,0},{0,0,0,0}};
    __builtin_amdgcn_s_setprio(1);
    #pragma unroll
    for (int dblk = 0; dblk < 2; ++dblk)
      #pragma unroll
      for (int fj = 0; fj < 4; ++fj) {
        int j2 = fj * 16 + l;
        short8 kf = *(const short8*)&Ks[cur][j2 * 64 + (((dblk * 4 + g) ^ (j2 & 7)) << 3)];
        sa[fj] = __builtin_amdgcn_mfma_f32_16x16x32_bf16(qf[dblk], kf, sa[fj], 0, 0, 0);
      }
    __builtin_amdgcn_s_setprio(0);
    // softmax: bias = table-lerp(dist in regs) + mask
    float al_[4];
    #pragma unroll
    for (int reg = 0; reg < 4; ++reg) {
      float svr[4];
      #pragma unroll
      for (int fj = 0; fj < 4; ++fj) {
        float u = ddc[reg][fj] * ((float)TAB_ / MAXD);
        int it = (int)u;
        it = it < 0 ? 0 : (it > TAB_ - 1 ? TAB_ - 1 : it);
        float f = u - (float)it;
        float2 tv = tl2[it];
        float bias = tv.x + f * (tv.y - tv.x) + mfl[tt * KT + fj * 16 + l];
        svr[fj] = fmaf(sa[fj][reg], 0.125f, bias);
      }
      float rm = fmaxf(fmaxf(svr[0], svr[1]), fmaxf(svr[2], svr[3]));
      rm = fmaxf(rm, __shfl_xor(rm, 1, 64));
      rm = fmaxf(rm, __shfl_xor(rm, 2, 64));
      rm = fmaxf(rm, __shfl_xor(rm, 4, 64));
      rm = fmaxf(rm, __shfl_xor(rm, 8, 64));
      float mn = fmaxf(m_[reg], rm);
      float al = __expf(m_[reg] - mn);
      m_[reg] = mn;
      al_[reg] = al;
      float ps = 0.f;
      int qlq = 4 * g + reg;
      #pragma unroll
      for (int fj = 0; fj < 4; ++fj) {
        float p = __expf(svr[fj] - mn);
        ps += p;
        int c = fj * 2 + (l >> 3);
        Ps[w][qlq * 64 + ((c ^ (qlq & 7)) << 3) + (l & 7)] = f2bf(p);
      }
      ps += __shfl_xor(ps, 1, 64);
      ps += __shfl_xor(ps, 2, 64);
      ps += __shfl_xor(ps, 4, 64);
      ps += __shfl_xor(ps, 8, 64);
      l_[reg] = l_[reg] * al + ps;
    }
    #pragma unroll
    for (int fd = 0; fd < 4; ++fd)
      #pragma unroll
      for (int reg = 0; reg < 4; ++reg) acc[fd][reg] *= al_[reg];
    // O += P V   (P A-frags, V^T B-frags)
    __builtin_amdgcn_s_setprio(1);
    #pragma unroll
    for (int jj = 0; jj < 2; ++jj) {
      short8 pa = *(const short8*)&Ps[w][l * 64 + (((jj * 4 + g) ^ (l & 7)) << 3)];
      #pragma unroll
      for (int fd = 0; fd < 4; ++fd) {
        int d2 = fd * 16 + l;
        short8 vf = *(const short8*)&Vt[cur][d2 * 64 + (((jj * 4 + g) ^ (d2 & 7)) << 3)];
        acc[fd] = __builtin_amdgcn_mfma_f32_16x16x32_bf16(pa, vf, acc[fd], 0, 0, 0);
      }
    }
    __builtin_amdgcn_s_setprio(0);
    // stage tile tt+1 into the other buffer (no race: readers use buf cur)
    if (tt + 1 < NTH) {
      int nb = cur ^ 1;
      stK(nb, k0a, jr); stK(nb, k1a, jr + 32);
      stV(nb, v0a, jr); stV(nb, v1a, jr + 32);
      #pragma unroll
      for (int reg = 0; reg < 4; ++reg)
        #pragma unroll
        for (int fj = 0; fj < 4; ++fj) ddc[reg][fj] = ddn[reg][fj];
    }
    __syncthreads();
    cur ^= 1;
  }
  // epilogue: unnormalized partials + (m,l)
  const size_t pbase = (((size_t)(b * NJH + jh) * NH_ + h) * N_) + i0;
  #pragma unroll
  for (int reg = 0; reg < 4; ++reg) {
    int rowl = w * 16 + 4 * g + reg;
    float* op = Op + (pbase + rowl) * HD_ + l;
    #pragma unroll
    for (int fd = 0; fd < 4; ++fd) op[fd * 16] = acc[fd][reg];
    if (l == 0) ml[pbase + rowl] = make_float2(m_[reg], l_[reg]);
  }
}

// ---------------- combine j-split partials ----------------
__global__ __launch_bounds__(256) void comb_k(const float* __restrict__ Op,
                                              const float2* __restrict__ ml,
                                              ushort* __restrict__ ao) {
  int idx = blockIdx.x * 256 + threadIdx.x;
  int row = idx >> 4;
  int dq = (idx & 15) * 4;
  int b = row >> 13, h = (row >> 10) & 7, n = row & 1023;
  size_t p0 = (((size_t)(b * NJH + 0) * NH_ + h) * N_) + n;
  size_t p1 = (((size_t)(b * NJH + 1) * NH_ + h) * N_) + n;
  float2 v0 = ml[p0], v1 = ml[p1];
  float M = fmaxf(v0.x, v1.x);
  float a0 = __expf(v0.x - M), a1 = __expf(v1.x - M);
  float inv = 1.0f / (v0.y * a0 + v1.y * a1);
  float4 O0 = *(const float4*)&Op[p0 * HD_ + dq];
  float4 O1 = *(const float4*)&Op[p1 * HD_ + dq];
  ushort4 o;
  o.x = f2bf((O0.x * a0 + O1.x * a1) * inv);
  o.y = f2bf((O0.y * a0 + O1.y * a1) * inv);
  o.z = f2bf((O0.z * a0 + O1.z * a1) * inv);
  o.w = f2bf((O0.w * a0 + O1.w * a1) * inv);
  *(ushort4*)&ao[((size_t)(b * N_ + n)) * H_ + h * HD_ + dq] = o;
}

extern "C" void kernel_launch(void* const* d_in, const int* in_sizes, int n_in,
                              void* d_out, int out_size, void* d_ws, size_t ws_size,
                              hipStream_t stream) {
  const float* x = (const float*)d_in[0];
  const float* distances = (const float*)d_in[1];
  const int* mask = (const int*)d_in[2];
  const float* widths = (const float*)d_in[3];
  const float* dp_w = (const float*)d_in[4];
  const float* dp_b = (const float*)d_in[5];
  const float* wq = (const float*)d_in[6];
  const float* bq = (const float*)d_in[7];
  const float* wk = (const float*)d_in[8];
  const float* bk = (const float*)d_in[9];
  const float* wv = (const float*)d_in[10];
  const float* bv = (const float*)d_in[11];
  const float* wo = (const float*)d_in[12];
  const float* bo = (const float*)d_in[13];
  const float* ln1_g = (const float*)d_in[14];
  const float* ln1_b = (const float*)d_in[15];
  const float* ln2_g = (const float*)d_in[16];
  const float* ln2_b = (const float*)d_in[17];
  const float* w1 = (const float*)d_in[18];
  const float* b1 = (const float*)d_in[19];
  const float* w2 = (const float*)d_in[20];
  const float* b2 = (const float*)d_in[21];
  float* out = (float*)d_out;
  float* wsf = (float*)d_ws;

  const size_t M1 = (size_t)1 << 20;
  ushort* qkvb = (ushort*)wsf;                       // 3M bf16 (V transposed)
  float* x1 = wsf + 2 * M1;                          // 1M f32
  ushort* hbuf = (ushort*)(wsf + 3 * M1);            // 4M bf16
  ushort* xn = (ushort*)(wsf + 5 * M1);              // 1M bf16
  ushort* xn2 = (ushort*)(wsf + 5 * M1 + M1 / 2);
  ushort* ao = (ushort*)(wsf + 6 * M1);              // 1M bf16
  ushort* wT4 = (ushort*)(wsf + 6 * M1 + M1 / 2);    // 4x 512x512 bf16
  ushort* w1T = (ushort*)(wsf + 7 * M1);             // [2048][512] bf16
  ushort* w2T = (ushort*)(wsf + 7 * M1 + M1 / 2);    // [512][2048] bf16
  float2* tab2 = (float2*)(wsf + 8 * M1);            // 8200 float2
  float* Op = wsf + 9 * M1;                          // 2M f32 attn partials
  float2* ml = (float2*)(wsf + 11 * M1);             // 32K float2

  prep_k<<<4129, 256, 0, stream>>>(wq, wk, wv, wo, w1, w2, wT4, w1T, w2T,
                                   widths, dp_w, dp_b, tab2, x, ln1_g, ln1_b, xn);

  mfma_gemm<64, 64, EPI_QKV><<<dim3(8, 32, 3), 256, 0, stream>>>(
      xn, wT4, bq, bk, bv, nullptr, qkvb, 512, 512, 512);

  attn_k<<<dim3(N_ / QT, NH_, B_ * NJH), 256, 0, stream>>>(
      qkvb, qkvb + M1, qkvb + 2 * M1, distances, mask, tab2, Op, ml);
  comb_k<<<1024, 256, 0, stream>>>(Op, ml, ao);

  // attn-O projection: in-block K-split x2, fused residual+bias -> x1 directly
  mfma_gemm2<EPI_RES><<<dim3(8, 32), 512, 0, stream>>>(
      ao, wT4 + (size_t)3 * 512 * 512, bo, x, x1, 256, 512, 512);
  ln2_k<<<B_ * N_, 128, 0, stream>>>(x1, ln2_g, ln2_b, xn2);

  // FFN1: 128x64 tiles -> 512 blocks (2/CU)
  mfma_gemm<128, 64, EPI_GELU><<<dim3(32, 16, 1), 256, 0, stream>>>(
      xn2, w1T, b1, b1, b1, nullptr, hbuf, 512, 512, 2048);

  // FFN2: in-block K-split x2, fully fused epilogue (resid + bias -> out)
  mfma_gemm2<EPI_RES><<<dim3(8, 32), 512, 0, stream>>>(
      hbuf, w2T, b2, x1, out, 1024, 2048, 512);
}